// Round 2
// baseline (1793.481 us; speedup 1.0000x reference)
//
#include <hip/hip_runtime.h>

#define B_ 32
#define H_ 56
#define W_ 56
#define N_ 3136
#define C_ 256
#define NH_ 8
#define HD_ 32
#define A_ 49
#define SCALE_ 0.17677669529663687f

typedef unsigned short u16;

__device__ __forceinline__ float b2f(u16 u) {
  union { unsigned int i; float f; } x; x.i = ((unsigned int)u) << 16; return x.f;
}
__device__ __forceinline__ u16 f2b(float f) {
  union { float f; unsigned int i; } x; x.f = f;
  unsigned int u = x.i;
  u += 0x7fffu + ((u >> 16) & 1u);   // RNE
  return (u16)(u >> 16);
}

// ---------------------------------------------------------------------------
// Bias precompute: position_bias [NH][A][N], agent_bias [NH][N][A]
// bilinear 7x7 -> 56x56, half-pixel, edge clamp (== jax renormalized triangle)
// ---------------------------------------------------------------------------
__global__ __launch_bounds__(256)
void bias_kernel(const float* __restrict__ an, const float* __restrict__ na,
                 const float* __restrict__ ah, const float* __restrict__ aw,
                 const float* __restrict__ ha, const float* __restrict__ wa,
                 float* __restrict__ posb, float* __restrict__ agb)
{
  const int hh = blockIdx.x / A_;
  const int ag = blockIdx.x % A_;
  __shared__ float an7[A_], na7[A_], ahv[H_], awv[W_], hav[H_], wav[W_];
  const int tid = threadIdx.x;
  if (tid < A_) {
    an7[tid] = an[(hh*A_ + ag)*A_ + tid];
    na7[tid] = na[(hh*A_ + ag)*A_ + tid];
  }
  if (tid < H_) {
    ahv[tid] = ah[(hh*A_ + ag)*H_ + tid];   // (1,NH,A,56,1)
    awv[tid] = aw[(hh*A_ + ag)*W_ + tid];   // (1,NH,A,1,56)
    hav[tid] = ha[(hh*H_ + tid)*A_ + ag];   // (1,NH,56,1,A)
    wav[tid] = wa[(hh*W_ + tid)*A_ + ag];   // (1,NH,1,56,A)
  }
  __syncthreads();
  for (int t = tid; t < N_; t += 256) {
    const int ty = t / W_, tx = t % W_;
    const float py = (ty + 0.5f)*0.125f - 0.5f;
    const float px = (tx + 0.5f)*0.125f - 0.5f;
    const int iy = (int)floorf(py), ix = (int)floorf(px);
    const float fy = py - (float)iy, fx = px - (float)ix;
    const int iy0 = min(max(iy, 0), 6), iy1 = min(iy + 1, 6);
    const int ix0 = min(max(ix, 0), 6), ix1 = min(ix + 1, 6);
    const float w00 = (1.f-fy)*(1.f-fx), w01 = (1.f-fy)*fx;
    const float w10 = fy*(1.f-fx),       w11 = fy*fx;
    const float ban = w00*an7[iy0*7+ix0] + w01*an7[iy0*7+ix1]
                    + w10*an7[iy1*7+ix0] + w11*an7[iy1*7+ix1];
    const float bna = w00*na7[iy0*7+ix0] + w01*na7[iy0*7+ix1]
                    + w10*na7[iy1*7+ix0] + w11*na7[iy1*7+ix1];
    posb[((size_t)(hh*A_ + ag))*N_ + t] = ban + ahv[ty] + awv[tx];
    agb[((size_t)hh*N_ + t)*A_ + ag]    = bna + hav[ty] + wav[tx];
  }
}

// ---------------------------------------------------------------------------
// QKV GEMM: X[100352,256] @ W[256,768] + b, scatter-epilogue to bf16
// q/k/v each laid out [b][nh][t][hd]
// ---------------------------------------------------------------------------
__global__ __launch_bounds__(256)
void gemm_qkv_kernel(const float* __restrict__ X, const float* __restrict__ W,
                     const float* __restrict__ bias,
                     u16* __restrict__ q, u16* __restrict__ k, u16* __restrict__ v)
{
  constexpr int BM=64, BN=64, BK=16, KD=256, ND=768;
  __shared__ float As[BK][BM+4];   // As[k][m], pad 4 keeps 16B align + kills wr conflicts
  __shared__ float Bs[BK][BN];
  const int tid = threadIdx.x;
  const int m0 = blockIdx.y * BM, n0 = blockIdx.x * BN;
  const int tx = tid & 15, ty = tid >> 4;
  float acc[4][4] = {};
  for (int k0 = 0; k0 < KD; k0 += BK) {
    __syncthreads();
    {
      const int col = tid & 15, row0 = tid >> 4;
      #pragma unroll
      for (int r = 0; r < 4; ++r) {
        const int row = row0 + r*16;
        As[col][row] = X[(size_t)(m0+row)*KD + (k0+col)];
      }
    }
    {
      const int col = tid & 63, row0 = tid >> 6;
      #pragma unroll
      for (int r = 0; r < 4; ++r) {
        const int row = row0 + r*4;
        Bs[row][col] = W[(size_t)(k0+row)*ND + (n0+col)];
      }
    }
    __syncthreads();
    #pragma unroll
    for (int kk = 0; kk < BK; ++kk) {
      const float4 a = *(const float4*)&As[kk][ty*4];
      const float4 b = *(const float4*)&Bs[kk][tx*4];
      acc[0][0] += a.x*b.x; acc[0][1] += a.x*b.y; acc[0][2] += a.x*b.z; acc[0][3] += a.x*b.w;
      acc[1][0] += a.y*b.x; acc[1][1] += a.y*b.y; acc[1][2] += a.y*b.z; acc[1][3] += a.y*b.w;
      acc[2][0] += a.z*b.x; acc[2][1] += a.z*b.y; acc[2][2] += a.z*b.z; acc[2][3] += a.z*b.w;
      acc[3][0] += a.w*b.x; acc[3][1] += a.w*b.y; acc[3][2] += a.w*b.z; acc[3][3] += a.w*b.w;
    }
  }
  #pragma unroll
  for (int i = 0; i < 4; ++i) {
    const int gm = m0 + ty*4 + i;
    const int bb = gm / N_, t = gm % N_;
    #pragma unroll
    for (int j = 0; j < 4; ++j) {
      const int gn = n0 + tx*4 + j;
      const float val = acc[i][j] + bias[gn];
      const int part = gn >> 8, cc = gn & 255, hh = cc >> 5, d = cc & 31;
      u16* dst = (part == 0) ? q : ((part == 1) ? k : v);
      dst[(((size_t)(bb*NH_ + hh))*N_ + t)*HD_ + d] = f2b(val);
    }
  }
}

// ---------------------------------------------------------------------------
// Agent pooling: 8x8 mean of q image -> agent [b][nh][49][32] (f32)
// ---------------------------------------------------------------------------
__global__ __launch_bounds__(64)
void pool_kernel(const u16* __restrict__ q, float* __restrict__ agent)
{
  const int blk = blockIdx.x;
  const int ag = blk % A_;
  const int rem = blk / A_;          // b*8+hh
  const int tid = threadIdx.x;
  const int d = tid & 31, half = tid >> 5;
  const int ay = ag / 7, ax = ag % 7;
  const size_t base = (size_t)rem * N_ * HD_;
  float s = 0.f;
  #pragma unroll
  for (int it = 0; it < 32; ++it) {
    const int yy = half*4 + (it >> 3), xx = it & 7;
    const int t = (ay*8 + yy)*W_ + ax*8 + xx;
    s += b2f(q[base + (size_t)t*HD_ + d]);
  }
  s += __shfl_down(s, 32, 64);
  if (tid < 32) agent[(size_t)rem*A_*HD_ + ag*HD_ + d] = s * (1.f/64.f);
}

// ---------------------------------------------------------------------------
// Stage 1: agent_attn = softmax(agent*scale @ K^T + posb); agent_v = attn @ V
// one block per (b,hh); flash-style online softmax over 49 tiles of 64 keys
// ---------------------------------------------------------------------------
__global__ __launch_bounds__(256)
void stage1_kernel(const u16* __restrict__ kmat, const u16* __restrict__ vmat,
                   const float* __restrict__ agent, const float* __restrict__ posb,
                   float* __restrict__ agentv)
{
  constexpr int TN = 64;                 // 3136 = 49 * 64 exactly
  __shared__ float As[A_][HD_];
  __shared__ float Ks[TN][HD_+1];
  __shared__ float Vs[TN][HD_];
  __shared__ float S[A_][TN+1];
  __shared__ float accs[A_*HD_];
  __shared__ float mrow[A_], lrow[A_], frow[A_];
  const int tid = threadIdx.x;
  const int b = blockIdx.x >> 3, hh = blockIdx.x & 7;
  const size_t kvbase = ((size_t)(b*NH_ + hh))*N_*HD_;
  const size_t agbase = ((size_t)(b*NH_ + hh))*A_*HD_;
  for (int i = tid; i < A_*HD_; i += 256) {
    (&As[0][0])[i] = agent[agbase + i] * SCALE_;
    accs[i] = 0.f;
  }
  if (tid < A_) { mrow[tid] = -1e30f; lrow[tid] = 0.f; }
  const float* pb = posb + (size_t)hh*A_*N_;

  for (int t0 = 0; t0 < N_; t0 += TN) {
    __syncthreads();
    for (int i4 = tid; i4 < TN*(HD_/4); i4 += 256) {
      const int tt = i4 >> 3, d4 = (i4 & 7) * 4;
      const size_t g = kvbase + (size_t)(t0+tt)*HD_ + d4;
      const ushort4 ku = *(const ushort4*)&kmat[g];
      const ushort4 vu = *(const ushort4*)&vmat[g];
      Ks[tt][d4+0]=b2f(ku.x); Ks[tt][d4+1]=b2f(ku.y); Ks[tt][d4+2]=b2f(ku.z); Ks[tt][d4+3]=b2f(ku.w);
      Vs[tt][d4+0]=b2f(vu.x); Vs[tt][d4+1]=b2f(vu.y); Vs[tt][d4+2]=b2f(vu.z); Vs[tt][d4+3]=b2f(vu.w);
    }
    __syncthreads();
    for (int idx = tid; idx < A_*TN; idx += 256) {
      const int ag = idx >> 6, tt = idx & 63;
      float s = 0.f;
      #pragma unroll
      for (int d = 0; d < HD_; ++d) s += As[ag][d] * Ks[tt][d];
      S[ag][tt] = s + pb[(size_t)ag*N_ + t0 + tt];
    }
    __syncthreads();
    if (tid < A_) {
      float rm = -1e30f;
      #pragma unroll 8
      for (int tt = 0; tt < TN; ++tt) rm = fmaxf(rm, S[tid][tt]);
      const float nm = fmaxf(mrow[tid], rm);
      const float f = __expf(mrow[tid] - nm);
      frow[tid] = f; mrow[tid] = nm; lrow[tid] *= f;
    }
    __syncthreads();
    for (int idx = tid; idx < A_*TN; idx += 256) {
      const int ag = idx >> 6, tt = idx & 63;
      S[ag][tt] = __expf(S[ag][tt] - mrow[ag]);
    }
    __syncthreads();
    if (tid < A_) {
      float rs = 0.f;
      #pragma unroll 8
      for (int tt = 0; tt < TN; ++tt) rs += S[tid][tt];
      lrow[tid] += rs;
    }
    for (int idx = tid; idx < A_*HD_; idx += 256) {
      const int ag = idx >> 5, d = idx & 31;
      float s = 0.f;
      #pragma unroll 8
      for (int tt = 0; tt < TN; ++tt) s += S[ag][tt] * Vs[tt][d];
      accs[idx] = accs[idx] * frow[ag] + s;
    }
  }
  __syncthreads();
  for (int idx = tid; idx < A_*HD_; idx += 256)
    agentv[agbase + idx] = accs[idx] / lrow[idx >> 5];
}

// ---------------------------------------------------------------------------
// Stage 2: q_attn = softmax(q*scale @ agent^T + agb); out = q_attn @ agent_v
// one thread per token; writes pre[b][t][c]
// ---------------------------------------------------------------------------
__global__ __launch_bounds__(128)
void stage2_kernel(const u16* __restrict__ qmat, const float* __restrict__ agent,
                   const float* __restrict__ agentv, const float* __restrict__ agb,
                   float* __restrict__ pre)
{
  __shared__ float As[A_][HD_];
  __shared__ float AVs[A_][HD_];
  __shared__ float S2[128*A_];
  const int tid = threadIdx.x;
  const int tile = blockIdx.x;                  // 0..24
  const int b = blockIdx.y >> 3, hh = blockIdx.y & 7;
  const size_t agbase = ((size_t)(b*NH_ + hh))*A_*HD_;
  for (int i = tid; i < A_*HD_; i += 128) {
    (&As[0][0])[i]  = agent[agbase + i] * SCALE_;
    (&AVs[0][0])[i] = agentv[agbase + i];
  }
  const int t0 = tile*128;
  const int ntok = min(128, N_ - t0);
  for (int i = tid; i < ntok*A_; i += 128)
    S2[i] = agb[((size_t)hh*N_ + t0)*A_ + i];   // [tt][ag] flat == global layout
  __syncthreads();
  if (tid < ntok) {
    const int t = t0 + tid;
    float4 qv[8];
    const ushort4* qp = (const ushort4*)&qmat[(((size_t)(b*NH_ + hh))*N_ + t)*HD_];
    #pragma unroll
    for (int i = 0; i < 8; ++i) {
      const ushort4 u = qp[i];
      qv[i] = make_float4(b2f(u.x), b2f(u.y), b2f(u.z), b2f(u.w));
    }
    float* srow = &S2[tid*A_];
    float mx = -1e30f;
    for (int ag = 0; ag < A_; ++ag) {
      const float4* arow = (const float4*)&As[ag][0];
      float s = 0.f;
      #pragma unroll
      for (int i = 0; i < 8; ++i) {
        const float4 a = arow[i];
        s += qv[i].x*a.x + qv[i].y*a.y + qv[i].z*a.z + qv[i].w*a.w;
      }
      s += srow[ag];
      srow[ag] = s;
      mx = fmaxf(mx, s);
    }
    float sum = 0.f;
    float o[HD_];
    #pragma unroll
    for (int d = 0; d < HD_; ++d) o[d] = 0.f;
    for (int ag = 0; ag < A_; ++ag) {
      const float p = __expf(srow[ag] - mx);
      sum += p;
      const float4* vrow = (const float4*)&AVs[ag][0];
      #pragma unroll
      for (int i = 0; i < 8; ++i) {
        const float4 a = vrow[i];
        o[i*4+0] += p*a.x; o[i*4+1] += p*a.y; o[i*4+2] += p*a.z; o[i*4+3] += p*a.w;
      }
    }
    const float inv = 1.f / sum;
    float* op = &pre[((size_t)b*N_ + t)*C_ + hh*HD_];
    #pragma unroll
    for (int i = 0; i < 8; ++i)
      ((float4*)op)[i] = make_float4(o[i*4]*inv, o[i*4+1]*inv, o[i*4+2]*inv, o[i*4+3]*inv);
  }
}

// ---------------------------------------------------------------------------
// Depthwise 3x3 conv on v (SAME), accumulates into pre[b][t][c]
// one block per (b,hh,y)
// ---------------------------------------------------------------------------
__global__ __launch_bounds__(256)
void dwc_kernel(const u16* __restrict__ v, const float* __restrict__ w9,
                const float* __restrict__ db, float* __restrict__ pre)
{
  const int blk = blockIdx.x;
  const int y = blk % H_;
  const int rem = blk / H_;            // b*8+hh
  const int hh = rem & 7, b = rem >> 3;
  const int tid = threadIdx.x;
  __shared__ float Vr[3*W_*HD_];
  const size_t vbase = (size_t)rem * N_ * HD_;
  for (int i = tid; i < 3*W_*HD_; i += 256) {
    const int r = i / (W_*HD_);
    const int rest = i - r*(W_*HD_);
    const int yy = y + r - 1;
    Vr[i] = (yy >= 0 && yy < H_) ? b2f(v[vbase + (size_t)yy*W_*HD_ + rest]) : 0.f;
  }
  __syncthreads();
  const int d = tid & 31, xg = tid >> 5;
  const int c = hh*HD_ + d;
  float wr[9];
  #pragma unroll
  for (int j = 0; j < 9; ++j) wr[j] = w9[c*9 + j];
  const float bias = db[c];
  for (int x = xg; x < W_; x += 8) {
    float s = bias;
    #pragma unroll
    for (int ky = 0; ky < 3; ++ky) {
      #pragma unroll
      for (int kx = 0; kx < 3; ++kx) {
        const int xx = x + kx - 1;
        if (xx >= 0 && xx < W_) s += Vr[(ky*W_ + xx)*HD_ + d] * wr[ky*3 + kx];
      }
    }
    pre[((size_t)b*N_ + y*W_ + x)*C_ + c] += s;
  }
}

// ---------------------------------------------------------------------------
// Proj GEMM: pre[100352,256] @ proj_w[256,256] + b -> d_out (f32)
// ---------------------------------------------------------------------------
__global__ __launch_bounds__(256)
void gemm_proj_kernel(const float* __restrict__ X, const float* __restrict__ W,
                      const float* __restrict__ bias, float* __restrict__ out)
{
  constexpr int BM=64, BN=64, BK=16, KD=256, ND=256;
  __shared__ float As[BK][BM+4];
  __shared__ float Bs[BK][BN];
  const int tid = threadIdx.x;
  const int m0 = blockIdx.y * BM, n0 = blockIdx.x * BN;
  const int tx = tid & 15, ty = tid >> 4;
  float acc[4][4] = {};
  for (int k0 = 0; k0 < KD; k0 += BK) {
    __syncthreads();
    {
      const int col = tid & 15, row0 = tid >> 4;
      #pragma unroll
      for (int r = 0; r < 4; ++r) {
        const int row = row0 + r*16;
        As[col][row] = X[(size_t)(m0+row)*KD + (k0+col)];
      }
    }
    {
      const int col = tid & 63, row0 = tid >> 6;
      #pragma unroll
      for (int r = 0; r < 4; ++r) {
        const int row = row0 + r*4;
        Bs[row][col] = W[(size_t)(k0+row)*ND + (n0+col)];
      }
    }
    __syncthreads();
    #pragma unroll
    for (int kk = 0; kk < BK; ++kk) {
      const float4 a = *(const float4*)&As[kk][ty*4];
      const float4 b = *(const float4*)&Bs[kk][tx*4];
      acc[0][0] += a.x*b.x; acc[0][1] += a.x*b.y; acc[0][2] += a.x*b.z; acc[0][3] += a.x*b.w;
      acc[1][0] += a.y*b.x; acc[1][1] += a.y*b.y; acc[1][2] += a.y*b.z; acc[1][3] += a.y*b.w;
      acc[2][0] += a.z*b.x; acc[2][1] += a.z*b.y; acc[2][2] += a.z*b.z; acc[2][3] += a.z*b.w;
      acc[3][0] += a.w*b.x; acc[3][1] += a.w*b.y; acc[3][2] += a.w*b.z; acc[3][3] += a.w*b.w;
    }
  }
  #pragma unroll
  for (int i = 0; i < 4; ++i) {
    const int gm = m0 + ty*4 + i;
    const int gn0 = n0 + tx*4;
    const float4 o = make_float4(acc[i][0] + bias[gn0+0], acc[i][1] + bias[gn0+1],
                                 acc[i][2] + bias[gn0+2], acc[i][3] + bias[gn0+3]);
    *(float4*)&out[(size_t)gm*ND + gn0] = o;
  }
}

// ---------------------------------------------------------------------------
extern "C" void kernel_launch(void* const* d_in, const int* in_sizes, int n_in,
                              void* d_out, int out_size, void* d_ws, size_t ws_size,
                              hipStream_t stream)
{
  (void)in_sizes; (void)n_in; (void)out_size;
  const float* x     = (const float*)d_in[0];
  const float* qkvw  = (const float*)d_in[1];
  const float* qkvb  = (const float*)d_in[2];
  const float* projw = (const float*)d_in[3];
  const float* projb = (const float*)d_in[4];
  const float* dwcw  = (const float*)d_in[5];
  const float* dwcb  = (const float*)d_in[6];
  const float* an    = (const float*)d_in[7];
  const float* na    = (const float*)d_in[8];
  const float* ah    = (const float*)d_in[9];
  const float* aw    = (const float*)d_in[10];
  const float* ha    = (const float*)d_in[11];
  const float* wa    = (const float*)d_in[12];

  const size_t EL = (size_t)B_*NH_*N_*HD_;     // 25,690,112 elements = B*N*C
  char* ws = (char*)d_ws;
  u16*   qb    = (u16*)(ws);
  u16*   kb    = (u16*)(ws + EL*2);
  u16*   vb    = (u16*)(ws + EL*4);
  float* pre   = (float*)(ws + EL*6);
  float* posb  = (float*)(ws + EL*10);
  float* agb   = (float*)(ws + EL*10 + (size_t)NH_*A_*N_*4);
  float* agent = (float*)(ws + EL*10 + (size_t)NH_*A_*N_*8);
  float* agv   = (float*)(ws + EL*10 + (size_t)NH_*A_*N_*8 + (size_t)B_*NH_*A_*HD_*4);
  const size_t NEED = EL*10 + (size_t)NH_*A_*N_*8 + (size_t)B_*NH_*A_*HD_*8;
  if (ws_size < NEED) return;   // avoid OOB scratch writes; bench will flag mismatch

  bias_kernel<<<dim3(NH_*A_), dim3(256), 0, stream>>>(an, na, ah, aw, ha, wa, posb, agb);
  gemm_qkv_kernel<<<dim3(12, 1568), dim3(256), 0, stream>>>(x, qkvw, qkvb, qb, kb, vb);
  pool_kernel<<<dim3(B_*NH_*A_), dim3(64), 0, stream>>>(qb, agent);
  stage1_kernel<<<dim3(B_*NH_), dim3(256), 0, stream>>>(kb, vb, agent, posb, agv);
  stage2_kernel<<<dim3(25, B_*NH_), dim3(128), 0, stream>>>(qb, agent, agv, agb, pre);
  dwc_kernel<<<dim3(B_*NH_*H_), dim3(256), 0, stream>>>(vb, dwcw, dwcb, pre);
  gemm_proj_kernel<<<dim3(4, 1568), dim3(256), 0, stream>>>(pre, projw, projb, (float*)d_out);
}

// Round 3
// 737.561 us; speedup vs baseline: 2.4316x; 2.4316x over previous
//
#include <hip/hip_runtime.h>
#include <stdint.h>

#define B_ 32
#define H_ 56
#define W_ 56
#define N_ 3136
#define C_ 256
#define NH_ 8
#define HD_ 32
#define A_ 49
#define NCH_ 7
#define CHK_ 448
#define SCALE_ 0.17677669529663687f

typedef _Float16 h16;
typedef __attribute__((ext_vector_type(4))) _Float16 h16x4;
typedef __attribute__((ext_vector_type(8))) _Float16 h16x8;
typedef __attribute__((ext_vector_type(4))) float f32x4;

// global -> LDS direct DMA, 16B per lane (CK-style address-space casts)
__device__ __forceinline__ void gload16(const void* g, void* l) {
  __builtin_amdgcn_global_load_lds(
      (const __attribute__((address_space(1))) unsigned int*)(uintptr_t)g,
      (__attribute__((address_space(3))) unsigned int*)(unsigned int)(uintptr_t)l,
      16, 0, 0);
}

// ---------------------------------------------------------------------------
// Bias precompute: position_bias [NH][A][N], agent_bias [NH][N][A]
// ---------------------------------------------------------------------------
__global__ __launch_bounds__(256)
void bias_kernel(const float* __restrict__ an, const float* __restrict__ na,
                 const float* __restrict__ ah, const float* __restrict__ aw,
                 const float* __restrict__ ha, const float* __restrict__ wa,
                 float* __restrict__ posb, float* __restrict__ agb)
{
  const int hh = blockIdx.x / A_;
  const int ag = blockIdx.x % A_;
  __shared__ float an7[A_], na7[A_], ahv[H_], awv[W_], hav[H_], wav[W_];
  const int tid = threadIdx.x;
  if (tid < A_) {
    an7[tid] = an[(hh*A_ + ag)*A_ + tid];
    na7[tid] = na[(hh*A_ + ag)*A_ + tid];
  }
  if (tid < H_) {
    ahv[tid] = ah[(hh*A_ + ag)*H_ + tid];
    awv[tid] = aw[(hh*A_ + ag)*W_ + tid];
    hav[tid] = ha[(hh*H_ + tid)*A_ + ag];
    wav[tid] = wa[(hh*W_ + tid)*A_ + ag];
  }
  __syncthreads();
  for (int t = tid; t < N_; t += 256) {
    const int ty = t / W_, tx = t % W_;
    const float py = (ty + 0.5f)*0.125f - 0.5f;
    const float px = (tx + 0.5f)*0.125f - 0.5f;
    const int iy = (int)floorf(py), ix = (int)floorf(px);
    const float fy = py - (float)iy, fx = px - (float)ix;
    const int iy0 = min(max(iy, 0), 6), iy1 = min(iy + 1, 6);
    const int ix0 = min(max(ix, 0), 6), ix1 = min(ix + 1, 6);
    const float w00 = (1.f-fy)*(1.f-fx), w01 = (1.f-fy)*fx;
    const float w10 = fy*(1.f-fx),       w11 = fy*fx;
    const float ban = w00*an7[iy0*7+ix0] + w01*an7[iy0*7+ix1]
                    + w10*an7[iy1*7+ix0] + w11*an7[iy1*7+ix1];
    const float bna = w00*na7[iy0*7+ix0] + w01*na7[iy0*7+ix1]
                    + w10*na7[iy1*7+ix0] + w11*na7[iy1*7+ix1];
    posb[((size_t)(hh*A_ + ag))*N_ + t] = ban + ahv[ty] + awv[tx];
    agb[((size_t)hh*N_ + t)*A_ + ag]    = bna + hav[ty] + wav[tx];
  }
}

// ---------------------------------------------------------------------------
// f32 -> f16 conversion of x (grid-stride, 8 elems/thread/iter)
// ---------------------------------------------------------------------------
__global__ __launch_bounds__(256)
void convx_kernel(const float* __restrict__ x, h16* __restrict__ xh)
{
  const size_t nchunk = (size_t)B_*N_*C_/8;   // 3,211,264
  const size_t stride = (size_t)gridDim.x * 256;
  for (size_t i = blockIdx.x*256 + threadIdx.x; i < nchunk; i += stride) {
    const float4 u = ((const float4*)x)[i*2];
    const float4 v = ((const float4*)x)[i*2+1];
    h16x8 o;
    o[0]=(h16)u.x; o[1]=(h16)u.y; o[2]=(h16)u.z; o[3]=(h16)u.w;
    o[4]=(h16)v.x; o[5]=(h16)v.y; o[6]=(h16)v.z; o[7]=(h16)v.w;
    ((h16x8*)xh)[i] = o;
  }
}

// transpose+convert both weight matrices: wtq[768][256], wtp[256][256] (f16)
__global__ __launch_bounds__(256)
void convw_kernel(const float* __restrict__ qkvw, const float* __restrict__ projw,
                  h16* __restrict__ wtq, h16* __restrict__ wtp)
{
  const int bid = blockIdx.x, k = threadIdx.x;
  if (bid < 768) {
    wtq[bid*256 + k] = (h16)qkvw[(size_t)k*768 + bid];
  } else {
    const int n = bid - 768;
    wtp[n*256 + k] = (h16)projw[(size_t)k*256 + n];
  }
}

// ---------------------------------------------------------------------------
// f16 MFMA GEMM core: 128x128 tile, BK=32, 4 waves (2x2), gload_lds + XOR swz
// A: xh[M][256] f16 row-major; B: wt[N][256] f16 (pre-transposed)
// ---------------------------------------------------------------------------
__device__ __forceinline__ void gemm_tile_128(
    const h16* __restrict__ Ag, const h16* __restrict__ Bg,
    int m0, int n0, char* lds, f32x4 acc[4][4], int lane, int wr, int wc, int tid)
{
  // frag LDS byte offsets (constant across K-steps)
  int aoff[4], boff[4];
  #pragma unroll
  for (int r = 0; r < 4; ++r) {
    const int row = wr*64 + r*16 + (lane & 15);
    const int ps  = (lane >> 4) ^ ((row >> 1) & 3);
    aoff[r] = row*64 + ps*16;
  }
  #pragma unroll
  for (int c = 0; c < 4; ++c) {
    const int nrow = wc*64 + c*16 + (lane & 15);
    const int ps   = (lane >> 4) ^ ((nrow >> 1) & 3);
    boff[c] = 8192 + nrow*64 + ps*16;
  }
  // staging addresses: idx in [0,512) covers 128 rows x 4 slots of 16B
  const int i0 = tid, i1 = tid + 256;
  const int r0 = i0 >> 2, s0 = (i0 & 3) ^ ((r0 >> 1) & 3);
  const int r1 = i1 >> 2, s1 = (i1 & 3) ^ ((r1 >> 1) & 3);

  for (int k0 = 0; k0 < 256; k0 += 32) {
    __syncthreads();
    gload16(Ag + (size_t)(m0 + r0)*256 + k0 + s0*8, lds + i0*16);
    gload16(Ag + (size_t)(m0 + r1)*256 + k0 + s1*8, lds + i1*16);
    gload16(Bg + (size_t)(n0 + r0)*256 + k0 + s0*8, lds + 8192 + i0*16);
    gload16(Bg + (size_t)(n0 + r1)*256 + k0 + s1*8, lds + 8192 + i1*16);
    __syncthreads();
    h16x8 af[4], bf[4];
    #pragma unroll
    for (int r = 0; r < 4; ++r) af[r] = *(const h16x8*)(lds + aoff[r]);
    #pragma unroll
    for (int c = 0; c < 4; ++c) bf[c] = *(const h16x8*)(lds + boff[c]);
    #pragma unroll
    for (int r = 0; r < 4; ++r)
      #pragma unroll
      for (int c = 0; c < 4; ++c)
        acc[r][c] = __builtin_amdgcn_mfma_f32_16x16x32_f16(af[r], bf[c], acc[r][c], 0, 0, 0);
  }
}

// QKV: M=100352, N=768; scatter epilogue into q/k/v [b][h][t][d] f16
__global__ __launch_bounds__(256)
void gemm_qkv_mfma(const h16* __restrict__ xh, const h16* __restrict__ wtq,
                   const float* __restrict__ qkvb,
                   h16* __restrict__ q, h16* __restrict__ k, h16* __restrict__ v)
{
  __shared__ __align__(16) char lds[16384];
  const int tid = threadIdx.x, lane = tid & 63, wid = tid >> 6;
  const int wr = wid & 1, wc = wid >> 1;
  const int m0 = blockIdx.y * 128, n0 = blockIdx.x * 128;
  f32x4 acc[4][4] = {};
  gemm_tile_128(xh, wtq, m0, n0, lds, acc, lane, wr, wc, tid);
  #pragma unroll
  for (int r = 0; r < 4; ++r) {
    #pragma unroll
    for (int reg = 0; reg < 4; ++reg) {
      const int m = m0 + wr*64 + r*16 + (lane >> 4)*4 + reg;
      const int bb = m / N_, t = m % N_;
      #pragma unroll
      for (int c = 0; c < 4; ++c) {
        const int n = n0 + wc*64 + c*16 + (lane & 15);
        const float val = acc[r][c][reg] + qkvb[n];
        const int part = n >> 8, cc = n & 255, hh = cc >> 5, d = cc & 31;
        h16* dst = (part == 0) ? q : ((part == 1) ? k : v);
        dst[(((size_t)(bb*NH_ + hh))*N_ + t)*HD_ + d] = (h16)val;
      }
    }
  }
}

// Proj: M=100352, N=256; f32 output + bias
__global__ __launch_bounds__(256)
void gemm_proj_mfma(const h16* __restrict__ preh, const h16* __restrict__ wtp,
                    const float* __restrict__ projb, float* __restrict__ out)
{
  __shared__ __align__(16) char lds[16384];
  const int tid = threadIdx.x, lane = tid & 63, wid = tid >> 6;
  const int wr = wid & 1, wc = wid >> 1;
  const int m0 = blockIdx.y * 128, n0 = blockIdx.x * 128;
  f32x4 acc[4][4] = {};
  gemm_tile_128(preh, wtp, m0, n0, lds, acc, lane, wr, wc, tid);
  #pragma unroll
  for (int r = 0; r < 4; ++r) {
    #pragma unroll
    for (int reg = 0; reg < 4; ++reg) {
      const int m = m0 + wr*64 + r*16 + (lane >> 4)*4 + reg;
      #pragma unroll
      for (int c = 0; c < 4; ++c) {
        const int n = n0 + wc*64 + c*16 + (lane & 15);
        out[(size_t)m*256 + n] = acc[r][c][reg] + projb[n];
      }
    }
  }
}

// ---------------------------------------------------------------------------
// Agent pooling: 8x8 mean of q image -> agent [b][nh][49][32] (f32)
// ---------------------------------------------------------------------------
__global__ __launch_bounds__(64)
void pool_kernel(const h16* __restrict__ q, float* __restrict__ agent)
{
  const int blk = blockIdx.x;
  const int ag = blk % A_;
  const int rem = blk / A_;
  const int tid = threadIdx.x;
  const int d = tid & 31, half = tid >> 5;
  const int ay = ag / 7, ax = ag % 7;
  const size_t base = (size_t)rem * N_ * HD_;
  float s = 0.f;
  #pragma unroll
  for (int it = 0; it < 32; ++it) {
    const int yy = half*4 + (it >> 3), xx = it & 7;
    const int t = (ay*8 + yy)*W_ + ax*8 + xx;
    s += (float)q[base + (size_t)t*HD_ + d];
  }
  s += __shfl_down(s, 32, 64);
  if (tid < 32) agent[(size_t)rem*A_*HD_ + ag*HD_ + d] = s * (1.f/64.f);
}

// ---------------------------------------------------------------------------
// Stage 1a: split-K flash over 448-key chunks; writes partial (m, l, acc)
// grid = B*NH*7; inner structure identical to the proven full-N version
// ---------------------------------------------------------------------------
__global__ __launch_bounds__(256)
void stage1a_kernel(const h16* __restrict__ kmat, const h16* __restrict__ vmat,
                    const float* __restrict__ agent, const float* __restrict__ posb,
                    float* __restrict__ pm, float* __restrict__ pl, float* __restrict__ pacc)
{
  constexpr int TN = 64;
  __shared__ float As[A_][HD_];
  __shared__ float Ks[TN][HD_+1];
  __shared__ float Vs[TN][HD_];
  __shared__ float S[A_][TN+1];
  __shared__ float accs[A_*HD_];
  __shared__ float mrow[A_], lrow[A_], frow[A_];
  const int tid = threadIdx.x;
  const int bx = blockIdx.x;
  const int ch = bx % NCH_;
  const int rem = bx / NCH_;                   // b*8+hh
  const int hh = rem & 7;
  const size_t kvbase = (size_t)rem*N_*HD_;
  const size_t agbase = (size_t)rem*A_*HD_;
  for (int i = tid; i < A_*HD_; i += 256) {
    (&As[0][0])[i] = agent[agbase + i] * SCALE_;
    accs[i] = 0.f;
  }
  if (tid < A_) { mrow[tid] = -1e30f; lrow[tid] = 0.f; }
  const float* pb = posb + (size_t)hh*A_*N_;

  const int tbeg = ch * CHK_;
  for (int t0 = tbeg; t0 < tbeg + CHK_; t0 += TN) {
    __syncthreads();
    for (int i4 = tid; i4 < TN*(HD_/4); i4 += 256) {
      const int tt = i4 >> 3, d4 = (i4 & 7) * 4;
      const size_t g = kvbase + (size_t)(t0+tt)*HD_ + d4;
      const h16x4 ku = *(const h16x4*)&kmat[g];
      const h16x4 vu = *(const h16x4*)&vmat[g];
      Ks[tt][d4+0]=(float)ku[0]; Ks[tt][d4+1]=(float)ku[1]; Ks[tt][d4+2]=(float)ku[2]; Ks[tt][d4+3]=(float)ku[3];
      Vs[tt][d4+0]=(float)vu[0]; Vs[tt][d4+1]=(float)vu[1]; Vs[tt][d4+2]=(float)vu[2]; Vs[tt][d4+3]=(float)vu[3];
    }
    __syncthreads();
    for (int idx = tid; idx < A_*TN; idx += 256) {
      const int ag = idx >> 6, tt = idx & 63;
      float s = 0.f;
      #pragma unroll
      for (int d = 0; d < HD_; ++d) s += As[ag][d] * Ks[tt][d];
      S[ag][tt] = s + pb[(size_t)ag*N_ + t0 + tt];
    }
    __syncthreads();
    if (tid < A_) {
      float rm = -1e30f;
      #pragma unroll 8
      for (int tt = 0; tt < TN; ++tt) rm = fmaxf(rm, S[tid][tt]);
      const float nm = fmaxf(mrow[tid], rm);
      const float f = __expf(mrow[tid] - nm);
      frow[tid] = f; mrow[tid] = nm; lrow[tid] *= f;
    }
    __syncthreads();
    for (int idx = tid; idx < A_*TN; idx += 256) {
      const int ag = idx >> 6, tt = idx & 63;
      S[ag][tt] = __expf(S[ag][tt] - mrow[ag]);
    }
    __syncthreads();
    if (tid < A_) {
      float rs = 0.f;
      #pragma unroll 8
      for (int tt = 0; tt < TN; ++tt) rs += S[tid][tt];
      lrow[tid] += rs;
    }
    for (int idx = tid; idx < A_*HD_; idx += 256) {
      const int ag = idx >> 5, d = idx & 31;
      float s = 0.f;
      #pragma unroll 8
      for (int tt = 0; tt < TN; ++tt) s += S[ag][tt] * Vs[tt][d];
      accs[idx] = accs[idx] * frow[ag] + s;
    }
  }
  __syncthreads();
  for (int idx = tid; idx < A_*HD_; idx += 256)
    pacc[(size_t)bx*(A_*HD_) + idx] = accs[idx];
  if (tid < A_) { pm[bx*A_ + tid] = mrow[tid]; pl[bx*A_ + tid] = lrow[tid]; }
}

// Stage 1b: combine 7 chunk-partials -> agent_v
__global__ __launch_bounds__(256)
void stage1b_kernel(const float* __restrict__ pm, const float* __restrict__ pl,
                    const float* __restrict__ pacc, float* __restrict__ agv)
{
  const int rem = blockIdx.x;
  __shared__ float fs[NCH_*A_];
  const int tid = threadIdx.x;
  if (tid < A_) {
    float m = -1e30f;
    #pragma unroll
    for (int ch = 0; ch < NCH_; ++ch) m = fmaxf(m, pm[(rem*NCH_+ch)*A_ + tid]);
    float e[NCH_], l = 0.f;
    #pragma unroll
    for (int ch = 0; ch < NCH_; ++ch) {
      e[ch] = __expf(pm[(rem*NCH_+ch)*A_ + tid] - m);
      l += e[ch] * pl[(rem*NCH_+ch)*A_ + tid];
    }
    const float inv = 1.f / l;
    #pragma unroll
    for (int ch = 0; ch < NCH_; ++ch) fs[ch*A_ + tid] = e[ch] * inv;
  }
  __syncthreads();
  for (int idx = tid; idx < A_*HD_; idx += 256) {
    const int ag = idx >> 5;
    float s = 0.f;
    #pragma unroll
    for (int ch = 0; ch < NCH_; ++ch)
      s += fs[ch*A_ + ag] * pacc[((size_t)(rem*NCH_+ch))*(A_*HD_) + idx];
    agv[(size_t)rem*(A_*HD_) + idx] = s;
  }
}

// ---------------------------------------------------------------------------
// Stage 2: out = softmax(q*scale @ agent^T + agb) @ agent_v -> preh (f16)
// ---------------------------------------------------------------------------
__global__ __launch_bounds__(128)
void stage2_kernel(const h16* __restrict__ qmat, const float* __restrict__ agent,
                   const float* __restrict__ agentv, const float* __restrict__ agb,
                   h16* __restrict__ preh)
{
  __shared__ float As[A_][HD_];
  __shared__ float AVs[A_][HD_];
  __shared__ float S2[128*A_];
  const int tid = threadIdx.x;
  const int tile = blockIdx.x;
  const int b = blockIdx.y >> 3, hh = blockIdx.y & 7;
  const size_t agbase = ((size_t)(b*NH_ + hh))*A_*HD_;
  for (int i = tid; i < A_*HD_; i += 128) {
    (&As[0][0])[i]  = agent[agbase + i] * SCALE_;
    (&AVs[0][0])[i] = agentv[agbase + i];
  }
  const int t0 = tile*128;
  const int ntok = min(128, N_ - t0);
  for (int i = tid; i < ntok*A_; i += 128)
    S2[i] = agb[((size_t)hh*N_ + t0)*A_ + i];
  __syncthreads();
  if (tid < ntok) {
    const int t = t0 + tid;
    float qv[HD_];
    const h16x8* qp = (const h16x8*)&qmat[(((size_t)(b*NH_ + hh))*N_ + t)*HD_];
    #pragma unroll
    for (int i = 0; i < 4; ++i) {
      const h16x8 u = qp[i];
      #pragma unroll
      for (int j = 0; j < 8; ++j) qv[i*8+j] = (float)u[j];
    }
    float* srow = &S2[tid*A_];
    float mx = -1e30f;
    for (int ag = 0; ag < A_; ++ag) {
      const float* arow = &As[ag][0];
      float s = 0.f;
      #pragma unroll
      for (int d = 0; d < HD_; ++d) s += qv[d]*arow[d];
      s += srow[ag];
      srow[ag] = s;
      mx = fmaxf(mx, s);
    }
    float sum = 0.f;
    float o[HD_];
    #pragma unroll
    for (int d = 0; d < HD_; ++d) o[d] = 0.f;
    for (int ag = 0; ag < A_; ++ag) {
      const float p = __expf(srow[ag] - mx);
      sum += p;
      const float* vrow = &AVs[ag][0];
      #pragma unroll
      for (int d = 0; d < HD_; ++d) o[d] += p*vrow[d];
    }
    const float inv = 1.f / sum;
    h16* op = &preh[((size_t)b*N_ + t)*C_ + hh*HD_];
    #pragma unroll
    for (int i = 0; i < 4; ++i) {
      h16x8 w;
      #pragma unroll
      for (int j = 0; j < 8; ++j) w[j] = (h16)(o[i*8+j]*inv);
      ((h16x8*)op)[i] = w;
    }
  }
}

// ---------------------------------------------------------------------------
// Depthwise 3x3 conv on v; RMW preh in place (each elem touched by 1 thread)
// ---------------------------------------------------------------------------
__global__ __launch_bounds__(256)
void dwc_kernel(const h16* __restrict__ v, const float* __restrict__ w9,
                const float* __restrict__ db, h16* __restrict__ preh)
{
  const int blk = blockIdx.x;
  const int y = blk % H_;
  const int rem = blk / H_;
  const int hh = rem & 7, b = rem >> 3;
  const int tid = threadIdx.x;
  __shared__ float Vr[3*W_*HD_];
  const size_t vbase = (size_t)rem * N_ * HD_;
  for (int i = tid; i < 3*W_*HD_; i += 256) {
    const int r = i / (W_*HD_);
    const int rest = i - r*(W_*HD_);
    const int yy = y + r - 1;
    Vr[i] = (yy >= 0 && yy < H_) ? (float)v[vbase + (size_t)yy*W_*HD_ + rest] : 0.f;
  }
  __syncthreads();
  const int d = tid & 31, xg = tid >> 5;
  const int c = hh*HD_ + d;
  float wr[9];
  #pragma unroll
  for (int j = 0; j < 9; ++j) wr[j] = w9[c*9 + j];
  const float bias = db[c];
  for (int x = xg; x < W_; x += 8) {
    float s = bias;
    #pragma unroll
    for (int ky = 0; ky < 3; ++ky) {
      #pragma unroll
      for (int kx = 0; kx < 3; ++kx) {
        const int xx = x + kx - 1;
        if (xx >= 0 && xx < W_) s += Vr[(ky*W_ + xx)*HD_ + d] * wr[ky*3 + kx];
      }
    }
    const size_t idx = ((size_t)b*N_ + y*W_ + x)*C_ + c;
    preh[idx] = (h16)((float)preh[idx] + s);
  }
}

// ---------------------------------------------------------------------------
extern "C" void kernel_launch(void* const* d_in, const int* in_sizes, int n_in,
                              void* d_out, int out_size, void* d_ws, size_t ws_size,
                              hipStream_t stream)
{
  (void)in_sizes; (void)n_in; (void)out_size;
  const float* x     = (const float*)d_in[0];
  const float* qkvw  = (const float*)d_in[1];
  const float* qkvb  = (const float*)d_in[2];
  const float* projw = (const float*)d_in[3];
  const float* projb = (const float*)d_in[4];
  const float* dwcw  = (const float*)d_in[5];
  const float* dwcb  = (const float*)d_in[6];
  const float* an    = (const float*)d_in[7];
  const float* na    = (const float*)d_in[8];
  const float* ah    = (const float*)d_in[9];
  const float* aw    = (const float*)d_in[10];
  const float* ha    = (const float*)d_in[11];
  const float* wa    = (const float*)d_in[12];

  const size_t EL = (size_t)B_*N_*C_;          // 25,690,112
  char* ws = (char*)d_ws;
  h16*   qh    = (h16*)(ws);                                     // EL*2
  h16*   kh    = (h16*)(ws + EL*2);                              // EL*2 (reused as preh)
  h16*   vh    = (h16*)(ws + EL*4);                              // EL*2
  h16*   xh    = (h16*)(ws + EL*6);                              // EL*2 (reused for partials)
  float* posb  = (float*)(ws + EL*8);                            // NH*A*N*4
  float* agb   = (float*)(ws + EL*8 + (size_t)NH_*A_*N_*4);      // NH*A*N*4
  float* agent = (float*)(ws + EL*8 + (size_t)NH_*A_*N_*8);
  float* agv   = (float*)(ws + EL*8 + (size_t)NH_*A_*N_*8 + (size_t)B_*NH_*A_*HD_*4);
  h16*   wtq   = (h16*)(ws + EL*8 + (size_t)NH_*A_*N_*8 + (size_t)B_*NH_*A_*HD_*8);
  h16*   wtp   = (h16*)((char*)wtq + (size_t)768*256*2);
  const size_t NEED = EL*8 + (size_t)NH_*A_*N_*8 + (size_t)B_*NH_*A_*HD_*8
                    + (size_t)768*256*2 + (size_t)256*256*2;
  if (ws_size < NEED) return;

  // stage1 partials overlap the (dead-by-then) xh buffer
  float* pm   = (float*)xh;                                      // [1792][49]
  float* pl   = pm + (size_t)B_*NH_*NCH_*A_;
  float* pacc = pl + (size_t)B_*NH_*NCH_*A_;                     // [1792][1568]
  h16*   preh = kh;                                              // k dead after stage1a

  bias_kernel<<<dim3(NH_*A_), dim3(256), 0, stream>>>(an, na, ah, aw, ha, wa, posb, agb);
  convx_kernel<<<dim3(4096), dim3(256), 0, stream>>>(x, xh);
  convw_kernel<<<dim3(1024), dim3(256), 0, stream>>>(qkvw, projw, wtq, wtp);
  gemm_qkv_mfma<<<dim3(6, 784), dim3(256), 0, stream>>>(xh, wtq, qkvb, qh, kh, vh);
  pool_kernel<<<dim3(B_*NH_*A_), dim3(64), 0, stream>>>(qh, agent);
  stage1a_kernel<<<dim3(B_*NH_*NCH_), dim3(256), 0, stream>>>(kh, vh, agent, posb, pm, pl, pacc);
  stage1b_kernel<<<dim3(B_*NH_), dim3(256), 0, stream>>>(pm, pl, pacc, agv);
  stage2_kernel<<<dim3(25, B_*NH_), dim3(128), 0, stream>>>(qh, agent, agv, agb, preh);
  dwc_kernel<<<dim3(B_*NH_*H_), dim3(256), 0, stream>>>(vh, dwcw, dwcb, preh);
  gemm_proj_mfma<<<dim3(2, 784), dim3(256), 0, stream>>>(preh, wtp, projb, (float*)d_out);
}

// Round 4
// 491.343 us; speedup vs baseline: 3.6502x; 1.5011x over previous
//
#include <hip/hip_runtime.h>
#include <stdint.h>

#define B_ 32
#define H_ 56
#define W_ 56
#define N_ 3136
#define C_ 256
#define NH_ 8
#define HD_ 32
#define A_ 49
#define NCH_ 7
#define CHK_ 448
#define SCALE_ 0.17677669529663687f

typedef _Float16 h16;
typedef __attribute__((ext_vector_type(4))) _Float16 h16x4;
typedef __attribute__((ext_vector_type(8))) _Float16 h16x8;
typedef __attribute__((ext_vector_type(4))) float f32x4;

// global -> LDS direct DMA, 16B per lane
__device__ __forceinline__ void gload16(const void* g, void* l) {
  __builtin_amdgcn_global_load_lds(
      (const __attribute__((address_space(1))) unsigned int*)(uintptr_t)g,
      (__attribute__((address_space(3))) unsigned int*)(unsigned int)(uintptr_t)l,
      16, 0, 0);
}

// ---------------------------------------------------------------------------
// Bias precompute: position_bias [NH][A][N], agent_bias [NH][N][A]
// ---------------------------------------------------------------------------
__global__ __launch_bounds__(256)
void bias_kernel(const float* __restrict__ an, const float* __restrict__ na,
                 const float* __restrict__ ah, const float* __restrict__ aw,
                 const float* __restrict__ ha, const float* __restrict__ wa,
                 float* __restrict__ posb, float* __restrict__ agb)
{
  const int hh = blockIdx.x / A_;
  const int ag = blockIdx.x % A_;
  __shared__ float an7[A_], na7[A_], ahv[H_], awv[W_], hav[H_], wav[W_];
  const int tid = threadIdx.x;
  if (tid < A_) {
    an7[tid] = an[(hh*A_ + ag)*A_ + tid];
    na7[tid] = na[(hh*A_ + ag)*A_ + tid];
  }
  if (tid < H_) {
    ahv[tid] = ah[(hh*A_ + ag)*H_ + tid];
    awv[tid] = aw[(hh*A_ + ag)*W_ + tid];
    hav[tid] = ha[(hh*H_ + tid)*A_ + ag];
    wav[tid] = wa[(hh*W_ + tid)*A_ + ag];
  }
  __syncthreads();
  for (int t = tid; t < N_; t += 256) {
    const int ty = t / W_, tx = t % W_;
    const float py = (ty + 0.5f)*0.125f - 0.5f;
    const float px = (tx + 0.5f)*0.125f - 0.5f;
    const int iy = (int)floorf(py), ix = (int)floorf(px);
    const float fy = py - (float)iy, fx = px - (float)ix;
    const int iy0 = min(max(iy, 0), 6), iy1 = min(iy + 1, 6);
    const int ix0 = min(max(ix, 0), 6), ix1 = min(ix + 1, 6);
    const float w00 = (1.f-fy)*(1.f-fx), w01 = (1.f-fy)*fx;
    const float w10 = fy*(1.f-fx),       w11 = fy*fx;
    const float ban = w00*an7[iy0*7+ix0] + w01*an7[iy0*7+ix1]
                    + w10*an7[iy1*7+ix0] + w11*an7[iy1*7+ix1];
    const float bna = w00*na7[iy0*7+ix0] + w01*na7[iy0*7+ix1]
                    + w10*na7[iy1*7+ix0] + w11*na7[iy1*7+ix1];
    posb[((size_t)(hh*A_ + ag))*N_ + t] = ban + ahv[ty] + awv[tx];
    agb[((size_t)hh*N_ + t)*A_ + ag]    = bna + hav[ty] + wav[tx];
  }
}

// ---------------------------------------------------------------------------
// f32 -> f16 conversion of x
// ---------------------------------------------------------------------------
__global__ __launch_bounds__(256)
void convx_kernel(const float* __restrict__ x, h16* __restrict__ xh)
{
  const size_t nchunk = (size_t)B_*N_*C_/8;
  const size_t stride = (size_t)gridDim.x * 256;
  for (size_t i = blockIdx.x*256 + threadIdx.x; i < nchunk; i += stride) {
    const float4 u = ((const float4*)x)[i*2];
    const float4 v = ((const float4*)x)[i*2+1];
    h16x8 o;
    o[0]=(h16)u.x; o[1]=(h16)u.y; o[2]=(h16)u.z; o[3]=(h16)u.w;
    o[4]=(h16)v.x; o[5]=(h16)v.y; o[6]=(h16)v.z; o[7]=(h16)v.w;
    ((h16x8*)xh)[i] = o;
  }
}

// transpose+convert weight matrices: wtq[768][256], wtp[256][256] (f16)
__global__ __launch_bounds__(256)
void convw_kernel(const float* __restrict__ qkvw, const float* __restrict__ projw,
                  h16* __restrict__ wtq, h16* __restrict__ wtp)
{
  const int bid = blockIdx.x, k = threadIdx.x;
  if (bid < 768) {
    wtq[bid*256 + k] = (h16)qkvw[(size_t)k*768 + bid];
  } else {
    const int n = bid - 768;
    wtp[n*256 + k] = (h16)projw[(size_t)k*256 + n];
  }
}

// ---------------------------------------------------------------------------
// f16 MFMA GEMM core: 128x128 tile, BK=32, 4 waves (2x2)
// ---------------------------------------------------------------------------
__device__ __forceinline__ void gemm_tile_128(
    const h16* __restrict__ Ag, const h16* __restrict__ Bg,
    int m0, int n0, char* lds, f32x4 acc[4][4], int lane, int wr, int wc, int tid)
{
  int aoff[4], boff[4];
  #pragma unroll
  for (int r = 0; r < 4; ++r) {
    const int row = wr*64 + r*16 + (lane & 15);
    const int ps  = (lane >> 4) ^ ((row >> 1) & 3);
    aoff[r] = row*64 + ps*16;
  }
  #pragma unroll
  for (int c = 0; c < 4; ++c) {
    const int nrow = wc*64 + c*16 + (lane & 15);
    const int ps   = (lane >> 4) ^ ((nrow >> 1) & 3);
    boff[c] = 8192 + nrow*64 + ps*16;
  }
  const int i0 = tid, i1 = tid + 256;
  const int r0 = i0 >> 2, s0 = (i0 & 3) ^ ((r0 >> 1) & 3);
  const int r1 = i1 >> 2, s1 = (i1 & 3) ^ ((r1 >> 1) & 3);

  for (int k0 = 0; k0 < 256; k0 += 32) {
    __syncthreads();
    gload16(Ag + (size_t)(m0 + r0)*256 + k0 + s0*8, lds + i0*16);
    gload16(Ag + (size_t)(m0 + r1)*256 + k0 + s1*8, lds + i1*16);
    gload16(Bg + (size_t)(n0 + r0)*256 + k0 + s0*8, lds + 8192 + i0*16);
    gload16(Bg + (size_t)(n0 + r1)*256 + k0 + s1*8, lds + 8192 + i1*16);
    __syncthreads();
    h16x8 af[4], bf[4];
    #pragma unroll
    for (int r = 0; r < 4; ++r) af[r] = *(const h16x8*)(lds + aoff[r]);
    #pragma unroll
    for (int c = 0; c < 4; ++c) bf[c] = *(const h16x8*)(lds + boff[c]);
    #pragma unroll
    for (int r = 0; r < 4; ++r)
      #pragma unroll
      for (int c = 0; c < 4; ++c)
        acc[r][c] = __builtin_amdgcn_mfma_f32_16x16x32_f16(af[r], bf[c], acc[r][c], 0, 0, 0);
  }
}

__global__ __launch_bounds__(256)
void gemm_qkv_mfma(const h16* __restrict__ xh, const h16* __restrict__ wtq,
                   const float* __restrict__ qkvb,
                   h16* __restrict__ q, h16* __restrict__ k, h16* __restrict__ v)
{
  __shared__ __align__(16) char lds[16384];
  const int tid = threadIdx.x, lane = tid & 63, wid = tid >> 6;
  const int wr = wid & 1, wc = wid >> 1;
  const int m0 = blockIdx.y * 128, n0 = blockIdx.x * 128;
  f32x4 acc[4][4] = {};
  gemm_tile_128(xh, wtq, m0, n0, lds, acc, lane, wr, wc, tid);
  #pragma unroll
  for (int r = 0; r < 4; ++r) {
    #pragma unroll
    for (int reg = 0; reg < 4; ++reg) {
      const int m = m0 + wr*64 + r*16 + (lane >> 4)*4 + reg;
      const int bb = m / N_, t = m % N_;
      #pragma unroll
      for (int c = 0; c < 4; ++c) {
        const int n = n0 + wc*64 + c*16 + (lane & 15);
        const float val = acc[r][c][reg] + qkvb[n];
        const int part = n >> 8, cc = n & 255, hh = cc >> 5, d = cc & 31;
        h16* dst = (part == 0) ? q : ((part == 1) ? k : v);
        dst[(((size_t)(bb*NH_ + hh))*N_ + t)*HD_ + d] = (h16)val;
      }
    }
  }
}

__global__ __launch_bounds__(256)
void gemm_proj_mfma(const h16* __restrict__ preh, const h16* __restrict__ wtp,
                    const float* __restrict__ projb, float* __restrict__ out)
{
  __shared__ __align__(16) char lds[16384];
  const int tid = threadIdx.x, lane = tid & 63, wid = tid >> 6;
  const int wr = wid & 1, wc = wid >> 1;
  const int m0 = blockIdx.y * 128, n0 = blockIdx.x * 128;
  f32x4 acc[4][4] = {};
  gemm_tile_128(preh, wtp, m0, n0, lds, acc, lane, wr, wc, tid);
  #pragma unroll
  for (int r = 0; r < 4; ++r) {
    #pragma unroll
    for (int reg = 0; reg < 4; ++reg) {
      const int m = m0 + wr*64 + r*16 + (lane >> 4)*4 + reg;
      #pragma unroll
      for (int c = 0; c < 4; ++c) {
        const int n = n0 + wc*64 + c*16 + (lane & 15);
        out[(size_t)m*256 + n] = acc[r][c][reg] + projb[n];
      }
    }
  }
}

// ---------------------------------------------------------------------------
// Agent pooling: 8x8 mean of q image -> agent [b][nh][49][32] (f32)
// ---------------------------------------------------------------------------
__global__ __launch_bounds__(64)
void pool_kernel(const h16* __restrict__ q, float* __restrict__ agent)
{
  const int blk = blockIdx.x;
  const int ag = blk % A_;
  const int rem = blk / A_;
  const int tid = threadIdx.x;
  const int d = tid & 31, half = tid >> 5;
  const int ay = ag / 7, ax = ag % 7;
  const size_t base = (size_t)rem * N_ * HD_;
  float s = 0.f;
  #pragma unroll
  for (int it = 0; it < 32; ++it) {
    const int yy = half*4 + (it >> 3), xx = it & 7;
    const int t = (ay*8 + yy)*W_ + ax*8 + xx;
    s += (float)q[base + (size_t)t*HD_ + d];
  }
  s += __shfl_down(s, 32, 64);
  if (tid < 32) agent[(size_t)rem*A_*HD_ + ag*HD_ + d] = s * (1.f/64.f);
}

// ---------------------------------------------------------------------------
// Stage 1a (MFMA): per block (b,h,chunk): flash over 7 key-tiles of 64.
// M = 64 (49 agents + pad), QK^T + online softmax in regs + PV, all MFMA.
// Fragment convention (verified in the round-2 GEMM): A/B row = lane&15,
// k-chunk = (lane>>4)*8; C/D col = lane&15, row = (lane>>4)*4+reg.
// ---------------------------------------------------------------------------
__global__ __launch_bounds__(256)
void stage1a_mfma(const h16* __restrict__ kmat, const h16* __restrict__ vmat,
                  const float* __restrict__ agent, const float* __restrict__ posb,
                  float* __restrict__ pm, float* __restrict__ pl, float* __restrict__ pacc)
{
  __shared__ __align__(16) h16 Kl[64*32];   // [key][4 swizzled 8-half slots]
  __shared__ __align__(16) h16 Vt[32*72];   // [d][t], stride 72 halves (144B, 16B-aligned)
  __shared__ __align__(16) h16 Sl[64*72];   // [agent][key], stride 72 halves
  const int tid = threadIdx.x, lane = tid & 63, wid = tid >> 6;
  const int bx = blockIdx.x;
  const int ch = bx % NCH_;
  const int rem = bx / NCH_;                 // b*8+hh
  const int hh = rem & 7;
  const size_t kvbase = (size_t)rem * N_ * HD_;
  const size_t agbase = (size_t)rem * A_ * HD_;
  const float* pb = posb + (size_t)hh*A_*N_;

  // agent A-fragment, held in registers (f16, pre-scaled); pad rows zero
  const int arow = wid*16 + (lane & 15);
  const int kc = (lane >> 4) * 8;
  h16x8 a_ag = {};
  if (arow < A_) {
    #pragma unroll
    for (int j = 0; j < 8; ++j)
      a_ag[j] = (h16)(agent[agbase + (size_t)arow*HD_ + kc + j] * SCALE_);
  }

  const int r_k = tid >> 2;                        // staged key row
  const int s_k = (tid & 3) ^ ((r_k >> 1) & 3);    // swizzled logical k-chunk
  const int rowm = (lane >> 4) * 4;
  const int agrow0 = wid*16 + rowm;                // +reg = this lane's C rows

  float m_r[4], l_r[4];
  #pragma unroll
  for (int r = 0; r < 4; ++r) { m_r[r] = -1e30f; l_r[r] = 0.f; }
  f32x4 accv[2] = {};                              // PV accum (d-tiles 0/1)

  for (int it = 0; it < 7; ++it) {
    const int t0 = ch*CHK_ + it*64;
    __syncthreads();
    // stage K (direct to LDS, swizzled source), V (regs -> transposed LDS)
    gload16(kmat + kvbase + (size_t)(t0 + r_k)*HD_ + s_k*8, ((char*)Kl) + tid*16);
    const h16x8 vv = *(const h16x8*)&vmat[kvbase + (size_t)(t0 + lane)*HD_ + wid*8];
    #pragma unroll
    for (int j = 0; j < 8; ++j) Vt[(wid*8 + j)*72 + lane] = vv[j];
    __syncthreads();

    // QK^T: 4 key col-tiles
    float sv[4][4];                                // [reg][c]
    #pragma unroll
    for (int c = 0; c < 4; ++c) {
      const int kr = c*16 + (lane & 15);
      const int ph = (lane >> 4) ^ ((kr >> 1) & 3);
      const h16x8 bf = *(const h16x8*)&Kl[kr*32 + ph*8];
      const f32x4 sc = __builtin_amdgcn_mfma_f32_16x16x32_f16(a_ag, bf, (f32x4){0.f,0.f,0.f,0.f}, 0, 0, 0);
      #pragma unroll
      for (int reg = 0; reg < 4; ++reg) sv[reg][c] = sc[reg];
    }
    // + posb, online softmax per row (rows in reg dim; 16-lane col groups)
    #pragma unroll
    for (int reg = 0; reg < 4; ++reg) {
      const int ag = agrow0 + reg;
      if (ag < A_) {
        #pragma unroll
        for (int c = 0; c < 4; ++c)
          sv[reg][c] += pb[(size_t)ag*N_ + t0 + c*16 + (lane & 15)];
      } else {
        #pragma unroll
        for (int c = 0; c < 4; ++c) sv[reg][c] = -1e30f;
      }
      float rm = fmaxf(fmaxf(sv[reg][0], sv[reg][1]), fmaxf(sv[reg][2], sv[reg][3]));
      rm = fmaxf(rm, __shfl_xor(rm, 1));
      rm = fmaxf(rm, __shfl_xor(rm, 2));
      rm = fmaxf(rm, __shfl_xor(rm, 4));
      rm = fmaxf(rm, __shfl_xor(rm, 8));
      const float mn = fmaxf(m_r[reg], rm);
      const float f = __expf(m_r[reg] - mn);
      m_r[reg] = mn;
      float rs = 0.f;
      #pragma unroll
      for (int c = 0; c < 4; ++c) {
        const float p = __expf(sv[reg][c] - mn);
        sv[reg][c] = p;
        rs += p;
      }
      rs += __shfl_xor(rs, 1); rs += __shfl_xor(rs, 2);
      rs += __shfl_xor(rs, 4); rs += __shfl_xor(rs, 8);
      l_r[reg] = l_r[reg]*f + rs;
      accv[0][reg] *= f;
      accv[1][reg] *= f;
      // P row -> LDS f16 (bank-disjoint groups, <=2-way -> free)
      const int row = agrow0 + reg;
      #pragma unroll
      for (int c = 0; c < 4; ++c)
        Sl[row*72 + c*16 + (lane & 15)] = (h16)sv[reg][c];
    }
    __syncthreads();
    // PV: out[agent][d] += P[agent][t] * V[t][d]; K=64 -> 2 k-steps
    const int srow = wid*16 + (lane & 15);
    #pragma unroll
    for (int ks = 0; ks < 2; ++ks) {
      const h16x8 pf = *(const h16x8*)&Sl[srow*72 + ks*32 + (lane >> 4)*8];
      #pragma unroll
      for (int c2 = 0; c2 < 2; ++c2) {
        const int d = c2*16 + (lane & 15);
        const h16x8 vf = *(const h16x8*)&Vt[d*72 + ks*32 + (lane >> 4)*8];
        accv[c2] = __builtin_amdgcn_mfma_f32_16x16x32_f16(pf, vf, accv[c2], 0, 0, 0);
      }
    }
  }

  // write partials (unnormalized acc + per-row m, l)
  #pragma unroll
  for (int reg = 0; reg < 4; ++reg) {
    const int ag = agrow0 + reg;
    if (ag < A_) {
      if ((lane & 15) == 0) {
        pm[bx*A_ + ag] = m_r[reg];
        pl[bx*A_ + ag] = l_r[reg];
      }
      #pragma unroll
      for (int c2 = 0; c2 < 2; ++c2)
        pacc[(size_t)bx*(A_*HD_) + (size_t)ag*HD_ + c2*16 + (lane & 15)] = accv[c2][reg];
    }
  }
}

// Stage 1b: combine 7 chunk-partials -> agent_v
__global__ __launch_bounds__(256)
void stage1b_kernel(const float* __restrict__ pm, const float* __restrict__ pl,
                    const float* __restrict__ pacc, float* __restrict__ agv)
{
  const int rem = blockIdx.x;
  __shared__ float fs[NCH_*A_];
  const int tid = threadIdx.x;
  if (tid < A_) {
    float m = -1e30f;
    #pragma unroll
    for (int ch = 0; ch < NCH_; ++ch) m = fmaxf(m, pm[(rem*NCH_+ch)*A_ + tid]);
    float e[NCH_], l = 0.f;
    #pragma unroll
    for (int ch = 0; ch < NCH_; ++ch) {
      e[ch] = __expf(pm[(rem*NCH_+ch)*A_ + tid] - m);
      l += e[ch] * pl[(rem*NCH_+ch)*A_ + tid];
    }
    const float inv = 1.f / l;
    #pragma unroll
    for (int ch = 0; ch < NCH_; ++ch) fs[ch*A_ + tid] = e[ch] * inv;
  }
  __syncthreads();
  for (int idx = tid; idx < A_*HD_; idx += 256) {
    const int ag = idx >> 5;
    float s = 0.f;
    #pragma unroll
    for (int ch = 0; ch < NCH_; ++ch)
      s += fs[ch*A_ + ag] * pacc[((size_t)(rem*NCH_+ch))*(A_*HD_) + idx];
    agv[(size_t)rem*(A_*HD_) + idx] = s;
  }
}

// ---------------------------------------------------------------------------
// Stage 2: out = softmax(q*scale @ agent^T + agb) @ agent_v -> preh (f16)
// ---------------------------------------------------------------------------
__global__ __launch_bounds__(128)
void stage2_kernel(const h16* __restrict__ qmat, const float* __restrict__ agent,
                   const float* __restrict__ agentv, const float* __restrict__ agb,
                   h16* __restrict__ preh)
{
  __shared__ float As[A_][HD_];
  __shared__ float AVs[A_][HD_];
  __shared__ float S2[128*A_];
  const int tid = threadIdx.x;
  const int tile = blockIdx.x;
  const int b = blockIdx.y >> 3, hh = blockIdx.y & 7;
  const size_t agbase = ((size_t)(b*NH_ + hh))*A_*HD_;
  for (int i = tid; i < A_*HD_; i += 128) {
    (&As[0][0])[i]  = agent[agbase + i] * SCALE_;
    (&AVs[0][0])[i] = agentv[agbase + i];
  }
  const int t0 = tile*128;
  const int ntok = min(128, N_ - t0);
  for (int i = tid; i < ntok*A_; i += 128)
    S2[i] = agb[((size_t)hh*N_ + t0)*A_ + i];
  __syncthreads();
  if (tid < ntok) {
    const int t = t0 + tid;
    float qv[HD_];
    const h16x8* qp = (const h16x8*)&qmat[(((size_t)(b*NH_ + hh))*N_ + t)*HD_];
    #pragma unroll
    for (int i = 0; i < 4; ++i) {
      const h16x8 u = qp[i];
      #pragma unroll
      for (int j = 0; j < 8; ++j) qv[i*8+j] = (float)u[j];
    }
    float* srow = &S2[tid*A_];
    float mx = -1e30f;
    for (int ag = 0; ag < A_; ++ag) {
      const float* arow = &As[ag][0];
      float s = 0.f;
      #pragma unroll
      for (int d = 0; d < HD_; ++d) s += qv[d]*arow[d];
      s += srow[ag];
      srow[ag] = s;
      mx = fmaxf(mx, s);
    }
    float sum = 0.f;
    float o[HD_];
    #pragma unroll
    for (int d = 0; d < HD_; ++d) o[d] = 0.f;
    for (int ag = 0; ag < A_; ++ag) {
      const float p = __expf(srow[ag] - mx);
      sum += p;
      const float* vrow = &AVs[ag][0];
      #pragma unroll
      for (int d = 0; d < HD_; ++d) o[d] += p*vrow[d];
    }
    const float inv = 1.f / sum;
    h16* op = &preh[((size_t)b*N_ + t)*C_ + hh*HD_];
    #pragma unroll
    for (int i = 0; i < 4; ++i) {
      h16x8 w;
      #pragma unroll
      for (int j = 0; j < 8; ++j) w[j] = (h16)(o[i*8+j]*inv);
      ((h16x8*)op)[i] = w;
    }
  }
}

// ---------------------------------------------------------------------------
// Depthwise 3x3 conv on v; RMW preh in place
// ---------------------------------------------------------------------------
__global__ __launch_bounds__(256)
void dwc_kernel(const h16* __restrict__ v, const float* __restrict__ w9,
                const float* __restrict__ db, h16* __restrict__ preh)
{
  const int blk = blockIdx.x;
  const int y = blk % H_;
  const int rem = blk / H_;
  const int hh = rem & 7, b = rem >> 3;
  const int tid = threadIdx.x;
  __shared__ float Vr[3*W_*HD_];
  const size_t vbase = (size_t)rem * N_ * HD_;
  for (int i = tid; i < 3*W_*HD_; i += 256) {
    const int r = i / (W_*HD_);
    const int rest = i - r*(W_*HD_);
    const int yy = y + r - 1;
    Vr[i] = (yy >= 0 && yy < H_) ? (float)v[vbase + (size_t)yy*W_*HD_ + rest] : 0.f;
  }
  __syncthreads();
  const int d = tid & 31, xg = tid >> 5;
  const int c = hh*HD_ + d;
  float wr[9];
  #pragma unroll
  for (int j = 0; j < 9; ++j) wr[j] = w9[c*9 + j];
  const float bias = db[c];
  for (int x = xg; x < W_; x += 8) {
    float s = bias;
    #pragma unroll
    for (int ky = 0; ky < 3; ++ky) {
      #pragma unroll
      for (int kx = 0; kx < 3; ++kx) {
        const int xx = x + kx - 1;
        if (xx >= 0 && xx < W_) s += Vr[(ky*W_ + xx)*HD_ + d] * wr[ky*3 + kx];
      }
    }
    const size_t idx = ((size_t)b*N_ + y*W_ + x)*C_ + c;
    preh[idx] = (h16)((float)preh[idx] + s);
  }
}

// ---------------------------------------------------------------------------
extern "C" void kernel_launch(void* const* d_in, const int* in_sizes, int n_in,
                              void* d_out, int out_size, void* d_ws, size_t ws_size,
                              hipStream_t stream)
{
  (void)in_sizes; (void)n_in; (void)out_size;
  const float* x     = (const float*)d_in[0];
  const float* qkvw  = (const float*)d_in[1];
  const float* qkvb  = (const float*)d_in[2];
  const float* projw = (const float*)d_in[3];
  const float* projb = (const float*)d_in[4];
  const float* dwcw  = (const float*)d_in[5];
  const float* dwcb  = (const float*)d_in[6];
  const float* an    = (const float*)d_in[7];
  const float* na    = (const float*)d_in[8];
  const float* ah    = (const float*)d_in[9];
  const float* aw    = (const float*)d_in[10];
  const float* ha    = (const float*)d_in[11];
  const float* wa    = (const float*)d_in[12];

  const size_t EL = (size_t)B_*N_*C_;
  char* ws = (char*)d_ws;
  h16*   qh    = (h16*)(ws);
  h16*   kh    = (h16*)(ws + EL*2);
  h16*   vh    = (h16*)(ws + EL*4);
  h16*   xh    = (h16*)(ws + EL*6);
  float* posb  = (float*)(ws + EL*8);
  float* agb   = (float*)(ws + EL*8 + (size_t)NH_*A_*N_*4);
  float* agent = (float*)(ws + EL*8 + (size_t)NH_*A_*N_*8);
  float* agv   = (float*)(ws + EL*8 + (size_t)NH_*A_*N_*8 + (size_t)B_*NH_*A_*HD_*4);
  h16*   wtq   = (h16*)(ws + EL*8 + (size_t)NH_*A_*N_*8 + (size_t)B_*NH_*A_*HD_*8);
  h16*   wtp   = (h16*)((char*)wtq + (size_t)768*256*2);
  const size_t NEED = EL*8 + (size_t)NH_*A_*N_*8 + (size_t)B_*NH_*A_*HD_*8
                    + (size_t)768*256*2 + (size_t)256*256*2;
  if (ws_size < NEED) return;

  float* pm   = (float*)xh;
  float* pl   = pm + (size_t)B_*NH_*NCH_*A_;
  float* pacc = pl + (size_t)B_*NH_*NCH_*A_;
  h16*   preh = kh;

  bias_kernel<<<dim3(NH_*A_), dim3(256), 0, stream>>>(an, na, ah, aw, ha, wa, posb, agb);
  convx_kernel<<<dim3(4096), dim3(256), 0, stream>>>(x, xh);
  convw_kernel<<<dim3(1024), dim3(256), 0, stream>>>(qkvw, projw, wtq, wtp);
  gemm_qkv_mfma<<<dim3(6, 784), dim3(256), 0, stream>>>(xh, wtq, qkvb, qh, kh, vh);
  pool_kernel<<<dim3(B_*NH_*A_), dim3(64), 0, stream>>>(qh, agent);
  stage1a_mfma<<<dim3(B_*NH_*NCH_), dim3(256), 0, stream>>>(kh, vh, agent, posb, pm, pl, pacc);
  stage1b_kernel<<<dim3(B_*NH_), dim3(256), 0, stream>>>(pm, pl, pacc, agv);
  stage2_kernel<<<dim3(25, B_*NH_), dim3(128), 0, stream>>>(qh, agent, agv, agb, preh);
  dwc_kernel<<<dim3(B_*NH_*H_), dim3(256), 0, stream>>>(vh, dwcw, dwcb, preh);
  gemm_proj_mfma<<<dim3(2, 784), dim3(256), 0, stream>>>(preh, wtp, projb, (float*)d_out);
}

// Round 5
// 399.298 us; speedup vs baseline: 4.4916x; 1.2305x over previous
//
#include <hip/hip_runtime.h>
#include <stdint.h>

#define B_ 32
#define H_ 56
#define W_ 56
#define N_ 3136
#define C_ 256
#define NH_ 8
#define HD_ 32
#define A_ 49
#define NCH_ 7
#define CHK_ 448
#define SCALE_ 0.17677669529663687f

typedef _Float16 h16;
typedef __attribute__((ext_vector_type(4))) _Float16 h16x4;
typedef __attribute__((ext_vector_type(8))) _Float16 h16x8;
typedef __attribute__((ext_vector_type(4))) float f32x4;

// global -> LDS direct DMA, 16B per lane
__device__ __forceinline__ void gload16(const void* g, void* l) {
  __builtin_amdgcn_global_load_lds(
      (const __attribute__((address_space(1))) unsigned int*)(uintptr_t)g,
      (__attribute__((address_space(3))) unsigned int*)(unsigned int)(uintptr_t)l,
      16, 0, 0);
}

// ---------------------------------------------------------------------------
// Bias precompute: position_bias [NH][A][N], agent_bias TRANSPOSED [NH][A][N]
// ---------------------------------------------------------------------------
__global__ __launch_bounds__(256)
void bias_kernel(const float* __restrict__ an, const float* __restrict__ na,
                 const float* __restrict__ ah, const float* __restrict__ aw,
                 const float* __restrict__ ha, const float* __restrict__ wa,
                 float* __restrict__ posb, float* __restrict__ agbt)
{
  const int hh = blockIdx.x / A_;
  const int ag = blockIdx.x % A_;
  __shared__ float an7[A_], na7[A_], ahv[H_], awv[W_], hav[H_], wav[W_];
  const int tid = threadIdx.x;
  if (tid < A_) {
    an7[tid] = an[(hh*A_ + ag)*A_ + tid];
    na7[tid] = na[(hh*A_ + ag)*A_ + tid];
  }
  if (tid < H_) {
    ahv[tid] = ah[(hh*A_ + ag)*H_ + tid];
    awv[tid] = aw[(hh*A_ + ag)*W_ + tid];
    hav[tid] = ha[(hh*H_ + tid)*A_ + ag];
    wav[tid] = wa[(hh*W_ + tid)*A_ + ag];
  }
  __syncthreads();
  for (int t = tid; t < N_; t += 256) {
    const int ty = t / W_, tx = t % W_;
    const float py = (ty + 0.5f)*0.125f - 0.5f;
    const float px = (tx + 0.5f)*0.125f - 0.5f;
    const int iy = (int)floorf(py), ix = (int)floorf(px);
    const float fy = py - (float)iy, fx = px - (float)ix;
    const int iy0 = min(max(iy, 0), 6), iy1 = min(iy + 1, 6);
    const int ix0 = min(max(ix, 0), 6), ix1 = min(ix + 1, 6);
    const float w00 = (1.f-fy)*(1.f-fx), w01 = (1.f-fy)*fx;
    const float w10 = fy*(1.f-fx),       w11 = fy*fx;
    const float ban = w00*an7[iy0*7+ix0] + w01*an7[iy0*7+ix1]
                    + w10*an7[iy1*7+ix0] + w11*an7[iy1*7+ix1];
    const float bna = w00*na7[iy0*7+ix0] + w01*na7[iy0*7+ix1]
                    + w10*na7[iy1*7+ix0] + w11*na7[iy1*7+ix1];
    posb[((size_t)(hh*A_ + ag))*N_ + t] = ban + ahv[ty] + awv[tx];
    agbt[((size_t)(hh*A_ + ag))*N_ + t] = bna + hav[ty] + wav[tx];
  }
}

// ---------------------------------------------------------------------------
// f32 -> f16 conversion of x
// ---------------------------------------------------------------------------
__global__ __launch_bounds__(256)
void convx_kernel(const float* __restrict__ x, h16* __restrict__ xh)
{
  const size_t nchunk = (size_t)B_*N_*C_/8;
  const size_t stride = (size_t)gridDim.x * 256;
  for (size_t i = blockIdx.x*256 + threadIdx.x; i < nchunk; i += stride) {
    const float4 u = ((const float4*)x)[i*2];
    const float4 v = ((const float4*)x)[i*2+1];
    h16x8 o;
    o[0]=(h16)u.x; o[1]=(h16)u.y; o[2]=(h16)u.z; o[3]=(h16)u.w;
    o[4]=(h16)v.x; o[5]=(h16)v.y; o[6]=(h16)v.z; o[7]=(h16)v.w;
    ((h16x8*)xh)[i] = o;
  }
}

// transpose+convert weight matrices: wtq[768][256], wtp[256][256] (f16)
__global__ __launch_bounds__(256)
void convw_kernel(const float* __restrict__ qkvw, const float* __restrict__ projw,
                  h16* __restrict__ wtq, h16* __restrict__ wtp)
{
  const int bid = blockIdx.x, k = threadIdx.x;
  if (bid < 768) {
    wtq[bid*256 + k] = (h16)qkvw[(size_t)k*768 + bid];
  } else {
    const int n = bid - 768;
    wtp[n*256 + k] = (h16)projw[(size_t)k*256 + n];
  }
}

// ---------------------------------------------------------------------------
// f16 MFMA GEMM core: 128x128 tile, BK=32, 4 waves (2x2)
// ---------------------------------------------------------------------------
__device__ __forceinline__ void gemm_tile_128(
    const h16* __restrict__ Ag, const h16* __restrict__ Bg,
    int m0, int n0, char* lds, f32x4 acc[4][4], int lane, int wr, int wc, int tid)
{
  int aoff[4], boff[4];
  #pragma unroll
  for (int r = 0; r < 4; ++r) {
    const int row = wr*64 + r*16 + (lane & 15);
    const int ps  = (lane >> 4) ^ ((row >> 1) & 3);
    aoff[r] = row*64 + ps*16;
  }
  #pragma unroll
  for (int c = 0; c < 4; ++c) {
    const int nrow = wc*64 + c*16 + (lane & 15);
    const int ps   = (lane >> 4) ^ ((nrow >> 1) & 3);
    boff[c] = 8192 + nrow*64 + ps*16;
  }
  const int i0 = tid, i1 = tid + 256;
  const int r0 = i0 >> 2, s0 = (i0 & 3) ^ ((r0 >> 1) & 3);
  const int r1 = i1 >> 2, s1 = (i1 & 3) ^ ((r1 >> 1) & 3);

  for (int k0 = 0; k0 < 256; k0 += 32) {
    __syncthreads();
    gload16(Ag + (size_t)(m0 + r0)*256 + k0 + s0*8, lds + i0*16);
    gload16(Ag + (size_t)(m0 + r1)*256 + k0 + s1*8, lds + i1*16);
    gload16(Bg + (size_t)(n0 + r0)*256 + k0 + s0*8, lds + 8192 + i0*16);
    gload16(Bg + (size_t)(n0 + r1)*256 + k0 + s1*8, lds + 8192 + i1*16);
    __syncthreads();
    h16x8 af[4], bf[4];
    #pragma unroll
    for (int r = 0; r < 4; ++r) af[r] = *(const h16x8*)(lds + aoff[r]);
    #pragma unroll
    for (int c = 0; c < 4; ++c) bf[c] = *(const h16x8*)(lds + boff[c]);
    #pragma unroll
    for (int r = 0; r < 4; ++r)
      #pragma unroll
      for (int c = 0; c < 4; ++c)
        acc[r][c] = __builtin_amdgcn_mfma_f32_16x16x32_f16(af[r], bf[c], acc[r][c], 0, 0, 0);
  }
}

__global__ __launch_bounds__(256)
void gemm_qkv_mfma(const h16* __restrict__ xh, const h16* __restrict__ wtq,
                   const float* __restrict__ qkvb,
                   h16* __restrict__ q, h16* __restrict__ k, h16* __restrict__ v)
{
  __shared__ __align__(16) char lds[16384];
  const int tid = threadIdx.x, lane = tid & 63, wid = tid >> 6;
  const int wr = wid & 1, wc = wid >> 1;
  const int m0 = blockIdx.y * 128, n0 = blockIdx.x * 128;
  f32x4 acc[4][4] = {};
  gemm_tile_128(xh, wtq, m0, n0, lds, acc, lane, wr, wc, tid);
  #pragma unroll
  for (int r = 0; r < 4; ++r) {
    #pragma unroll
    for (int reg = 0; reg < 4; ++reg) {
      const int m = m0 + wr*64 + r*16 + (lane >> 4)*4 + reg;
      const int bb = m / N_, t = m % N_;
      #pragma unroll
      for (int c = 0; c < 4; ++c) {
        const int n = n0 + wc*64 + c*16 + (lane & 15);
        const float val = acc[r][c][reg] + qkvb[n];
        const int part = n >> 8, cc = n & 255, hh = cc >> 5, d = cc & 31;
        h16* dst = (part == 0) ? q : ((part == 1) ? k : v);
        dst[(((size_t)(bb*NH_ + hh))*N_ + t)*HD_ + d] = (h16)val;
      }
    }
  }
}

__global__ __launch_bounds__(256)
void gemm_proj_mfma(const h16* __restrict__ preh, const h16* __restrict__ wtp,
                    const float* __restrict__ projb, float* __restrict__ out)
{
  __shared__ __align__(16) char lds[16384];
  const int tid = threadIdx.x, lane = tid & 63, wid = tid >> 6;
  const int wr = wid & 1, wc = wid >> 1;
  const int m0 = blockIdx.y * 128, n0 = blockIdx.x * 128;
  f32x4 acc[4][4] = {};
  gemm_tile_128(preh, wtp, m0, n0, lds, acc, lane, wr, wc, tid);
  #pragma unroll
  for (int r = 0; r < 4; ++r) {
    #pragma unroll
    for (int reg = 0; reg < 4; ++reg) {
      const int m = m0 + wr*64 + r*16 + (lane >> 4)*4 + reg;
      #pragma unroll
      for (int c = 0; c < 4; ++c) {
        const int n = n0 + wc*64 + c*16 + (lane & 15);
        out[(size_t)m*256 + n] = acc[r][c][reg] + projb[n];
      }
    }
  }
}

// ---------------------------------------------------------------------------
// Agent pooling: 8x8 mean of q image -> agent [b][nh][49][32] (f32)
// ---------------------------------------------------------------------------
__global__ __launch_bounds__(64)
void pool_kernel(const h16* __restrict__ q, float* __restrict__ agent)
{
  const int blk = blockIdx.x;
  const int ag = blk % A_;
  const int rem = blk / A_;
  const int tid = threadIdx.x;
  const int d = tid & 31, half = tid >> 5;
  const int ay = ag / 7, ax = ag % 7;
  const size_t base = (size_t)rem * N_ * HD_;
  float s = 0.f;
  #pragma unroll
  for (int it = 0; it < 32; ++it) {
    const int yy = half*4 + (it >> 3), xx = it & 7;
    const int t = (ay*8 + yy)*W_ + ax*8 + xx;
    s += (float)q[base + (size_t)t*HD_ + d];
  }
  s += __shfl_down(s, 32, 64);
  if (tid < 32) agent[(size_t)rem*A_*HD_ + ag*HD_ + d] = s * (1.f/64.f);
}

// ---------------------------------------------------------------------------
// Stage 1a (MFMA): flash over 7 key-tiles of 64; M=64 (49 agents + pad)
// ---------------------------------------------------------------------------
__global__ __launch_bounds__(256)
void stage1a_mfma(const h16* __restrict__ kmat, const h16* __restrict__ vmat,
                  const float* __restrict__ agent, const float* __restrict__ posb,
                  float* __restrict__ pm, float* __restrict__ pl, float* __restrict__ pacc)
{
  __shared__ __align__(16) h16 Kl[64*32];
  __shared__ __align__(16) h16 Vt[32*72];
  __shared__ __align__(16) h16 Sl[64*72];
  const int tid = threadIdx.x, lane = tid & 63, wid = tid >> 6;
  const int bx = blockIdx.x;
  const int ch = bx % NCH_;
  const int rem = bx / NCH_;
  const int hh = rem & 7;
  const size_t kvbase = (size_t)rem * N_ * HD_;
  const size_t agbase = (size_t)rem * A_ * HD_;
  const float* pb = posb + (size_t)hh*A_*N_;

  const int arow = wid*16 + (lane & 15);
  const int kc = (lane >> 4) * 8;
  h16x8 a_ag = {};
  if (arow < A_) {
    #pragma unroll
    for (int j = 0; j < 8; ++j)
      a_ag[j] = (h16)(agent[agbase + (size_t)arow*HD_ + kc + j] * SCALE_);
  }

  const int r_k = tid >> 2;
  const int s_k = (tid & 3) ^ ((r_k >> 1) & 3);
  const int rowm = (lane >> 4) * 4;
  const int agrow0 = wid*16 + rowm;

  float m_r[4], l_r[4];
  #pragma unroll
  for (int r = 0; r < 4; ++r) { m_r[r] = -1e30f; l_r[r] = 0.f; }
  f32x4 accv[2] = {};

  for (int it = 0; it < 7; ++it) {
    const int t0 = ch*CHK_ + it*64;
    __syncthreads();
    gload16(kmat + kvbase + (size_t)(t0 + r_k)*HD_ + s_k*8, ((char*)Kl) + tid*16);
    const h16x8 vv = *(const h16x8*)&vmat[kvbase + (size_t)(t0 + lane)*HD_ + wid*8];
    #pragma unroll
    for (int j = 0; j < 8; ++j) Vt[(wid*8 + j)*72 + lane] = vv[j];
    __syncthreads();

    float sv[4][4];
    #pragma unroll
    for (int c = 0; c < 4; ++c) {
      const int kr = c*16 + (lane & 15);
      const int ph = (lane >> 4) ^ ((kr >> 1) & 3);
      const h16x8 bf = *(const h16x8*)&Kl[kr*32 + ph*8];
      const f32x4 sc = __builtin_amdgcn_mfma_f32_16x16x32_f16(a_ag, bf, (f32x4){0.f,0.f,0.f,0.f}, 0, 0, 0);
      #pragma unroll
      for (int reg = 0; reg < 4; ++reg) sv[reg][c] = sc[reg];
    }
    #pragma unroll
    for (int reg = 0; reg < 4; ++reg) {
      const int ag = agrow0 + reg;
      if (ag < A_) {
        #pragma unroll
        for (int c = 0; c < 4; ++c)
          sv[reg][c] += pb[(size_t)ag*N_ + t0 + c*16 + (lane & 15)];
      } else {
        #pragma unroll
        for (int c = 0; c < 4; ++c) sv[reg][c] = -1e30f;
      }
      float rm = fmaxf(fmaxf(sv[reg][0], sv[reg][1]), fmaxf(sv[reg][2], sv[reg][3]));
      rm = fmaxf(rm, __shfl_xor(rm, 1));
      rm = fmaxf(rm, __shfl_xor(rm, 2));
      rm = fmaxf(rm, __shfl_xor(rm, 4));
      rm = fmaxf(rm, __shfl_xor(rm, 8));
      const float mn = fmaxf(m_r[reg], rm);
      const float f = __expf(m_r[reg] - mn);
      m_r[reg] = mn;
      float rs = 0.f;
      #pragma unroll
      for (int c = 0; c < 4; ++c) {
        const float p = __expf(sv[reg][c] - mn);
        sv[reg][c] = p;
        rs += p;
      }
      rs += __shfl_xor(rs, 1); rs += __shfl_xor(rs, 2);
      rs += __shfl_xor(rs, 4); rs += __shfl_xor(rs, 8);
      l_r[reg] = l_r[reg]*f + rs;
      accv[0][reg] *= f;
      accv[1][reg] *= f;
      const int row = agrow0 + reg;
      #pragma unroll
      for (int c = 0; c < 4; ++c)
        Sl[row*72 + c*16 + (lane & 15)] = (h16)sv[reg][c];
    }
    __syncthreads();
    const int srow = wid*16 + (lane & 15);
    #pragma unroll
    for (int ks = 0; ks < 2; ++ks) {
      const h16x8 pf = *(const h16x8*)&Sl[srow*72 + ks*32 + (lane >> 4)*8];
      #pragma unroll
      for (int c2 = 0; c2 < 2; ++c2) {
        const int d = c2*16 + (lane & 15);
        const h16x8 vf = *(const h16x8*)&Vt[d*72 + ks*32 + (lane >> 4)*8];
        accv[c2] = __builtin_amdgcn_mfma_f32_16x16x32_f16(pf, vf, accv[c2], 0, 0, 0);
      }
    }
  }

  #pragma unroll
  for (int reg = 0; reg < 4; ++reg) {
    const int ag = agrow0 + reg;
    if (ag < A_) {
      if ((lane & 15) == 0) {
        pm[bx*A_ + ag] = m_r[reg];
        pl[bx*A_ + ag] = l_r[reg];
      }
      #pragma unroll
      for (int c2 = 0; c2 < 2; ++c2)
        pacc[(size_t)bx*(A_*HD_) + (size_t)ag*HD_ + c2*16 + (lane & 15)] = accv[c2][reg];
    }
  }
}

// Stage 1b: combine 7 chunk-partials -> agent_v
__global__ __launch_bounds__(256)
void stage1b_kernel(const float* __restrict__ pm, const float* __restrict__ pl,
                    const float* __restrict__ pacc, float* __restrict__ agv)
{
  const int rem = blockIdx.x;
  __shared__ float fs[NCH_*A_];
  const int tid = threadIdx.x;
  if (tid < A_) {
    float m = -1e30f;
    #pragma unroll
    for (int ch = 0; ch < NCH_; ++ch) m = fmaxf(m, pm[(rem*NCH_+ch)*A_ + tid]);
    float e[NCH_], l = 0.f;
    #pragma unroll
    for (int ch = 0; ch < NCH_; ++ch) {
      e[ch] = __expf(pm[(rem*NCH_+ch)*A_ + tid] - m);
      l += e[ch] * pl[(rem*NCH_+ch)*A_ + tid];
    }
    const float inv = 1.f / l;
    #pragma unroll
    for (int ch = 0; ch < NCH_; ++ch) fs[ch*A_ + tid] = e[ch] * inv;
  }
  __syncthreads();
  for (int idx = tid; idx < A_*HD_; idx += 256) {
    const int ag = idx >> 5;
    float s = 0.f;
    #pragma unroll
    for (int ch = 0; ch < NCH_; ++ch)
      s += fs[ch*A_ + ag] * pacc[((size_t)(rem*NCH_+ch))*(A_*HD_) + idx];
    agv[(size_t)rem*(A_*HD_) + idx] = s;
  }
}

// ---------------------------------------------------------------------------
// Stage 2 (MFMA): per wave 64 tokens x 64 agent-cols (49+pad).
// QK^T (16 MFMA) -> single-pass softmax (bias from agbt[h][a][t], float4)
// -> normalized P to per-wave LDS -> PV (16 MFMA) -> f16 stores.
// Only 2 staging barriers per block; compute phase barrier-free.
// ---------------------------------------------------------------------------
__global__ __launch_bounds__(256)
void stage2_mfma(const h16* __restrict__ qmat, const float* __restrict__ agent,
                 const float* __restrict__ agv, const float* __restrict__ agbt,
                 h16* __restrict__ preh)
{
  __shared__ __align__(16) char lds2[45568];
  h16* Asw = (h16*)lds2;                       // [64][32] agent, swizzled, padded
  h16* AVt = (h16*)(lds2 + 4096);              // [32][72] agent_v transposed, padded
  const int tid = threadIdx.x, lane = tid & 63, wid = tid >> 6;
  const int b = blockIdx.y >> 3, hh = blockIdx.y & 7;
  const size_t agbase = (size_t)(b*NH_ + hh)*A_*HD_;

  for (int i = tid; i < 64*32; i += 256) Asw[i] = (h16)0.f;
  for (int i = tid; i < 32*72; i += 256) AVt[i] = (h16)0.f;
  __syncthreads();
  for (int i = tid; i < A_*HD_; i += 256) {
    const int a = i >> 5, d = i & 31;
    Asw[a*32 + (((d >> 3) ^ ((a >> 1) & 3)))*8 + (d & 7)] = (h16)(agent[agbase + i] * SCALE_);
    AVt[d*72 + a] = (h16)agv[agbase + i];
  }
  __syncthreads();

  const int t0 = blockIdx.x*256 + wid*64;
  if (t0 >= N_) return;

  h16* Pl = (h16*)(lds2 + 8704 + wid*9216);    // per-wave [64][72]
  const h16* qbase = qmat + (size_t)(b*NH_ + hh)*N_*HD_;
  const float* agbt_h = agbt + (size_t)hh*A_*N_;
  const int l15 = lane & 15, g = lane >> 4;

  // B-frags for QK^T (agent), hoisted
  h16x8 bq[4];
  #pragma unroll
  for (int c = 0; c < 4; ++c) {
    const int a = c*16 + l15;
    const int ph = g ^ ((a >> 1) & 3);
    bq[c] = *(const h16x8*)&Asw[a*32 + ph*8];
  }
  // A-frags: q rows
  h16x8 aq[4];
  #pragma unroll
  for (int rt = 0; rt < 4; ++rt)
    aq[rt] = *(const h16x8*)&qbase[(size_t)(t0 + rt*16 + l15)*HD_ + g*8];

  // QK^T
  f32x4 sc[4][4];
  #pragma unroll
  for (int rt = 0; rt < 4; ++rt)
    #pragma unroll
    for (int c = 0; c < 4; ++c)
      sc[rt][c] = __builtin_amdgcn_mfma_f32_16x16x32_f16(aq[rt], bq[c], (f32x4){0.f,0.f,0.f,0.f}, 0, 0, 0);

  // bias + softmax (single pass over 49 cols) + normalized P -> LDS
  #pragma unroll
  for (int rt = 0; rt < 4; ++rt) {
    float sv[4][4];                            // [reg][c]
    #pragma unroll
    for (int c = 0; c < 4; ++c) {
      const int a = c*16 + l15;
      if (a < A_) {
        const float4 bias = *(const float4*)&agbt_h[(size_t)a*N_ + t0 + rt*16 + g*4];
        sv[0][c] = sc[rt][c][0] + bias.x;
        sv[1][c] = sc[rt][c][1] + bias.y;
        sv[2][c] = sc[rt][c][2] + bias.z;
        sv[3][c] = sc[rt][c][3] + bias.w;
      } else {
        sv[0][c] = sv[1][c] = sv[2][c] = sv[3][c] = -1e30f;
      }
    }
    #pragma unroll
    for (int reg = 0; reg < 4; ++reg) {
      float rm = fmaxf(fmaxf(sv[reg][0], sv[reg][1]), fmaxf(sv[reg][2], sv[reg][3]));
      rm = fmaxf(rm, __shfl_xor(rm, 1));
      rm = fmaxf(rm, __shfl_xor(rm, 2));
      rm = fmaxf(rm, __shfl_xor(rm, 4));
      rm = fmaxf(rm, __shfl_xor(rm, 8));
      float rs = 0.f;
      #pragma unroll
      for (int c = 0; c < 4; ++c) {
        const float p = __expf(sv[reg][c] - rm);
        sv[reg][c] = p;
        rs += p;
      }
      rs += __shfl_xor(rs, 1); rs += __shfl_xor(rs, 2);
      rs += __shfl_xor(rs, 4); rs += __shfl_xor(rs, 8);
      const float inv = 1.f / rs;
      const int row = rt*16 + g*4 + reg;
      #pragma unroll
      for (int c = 0; c < 4; ++c)
        Pl[row*72 + c*16 + l15] = (h16)(sv[reg][c] * inv);
    }
  }

  // PV: D[t][d] = P[t][a] * AV[a][d]
  h16x8 vf[2][2];
  #pragma unroll
  for (int ks = 0; ks < 2; ++ks)
    #pragma unroll
    for (int c2 = 0; c2 < 2; ++c2)
      vf[ks][c2] = *(const h16x8*)&AVt[(c2*16 + l15)*72 + ks*32 + g*8];

  f32x4 av[4][2] = {};
  #pragma unroll
  for (int rt = 0; rt < 4; ++rt) {
    #pragma unroll
    for (int ks = 0; ks < 2; ++ks) {
      const h16x8 pf = *(const h16x8*)&Pl[(rt*16 + l15)*72 + ks*32 + g*8];
      #pragma unroll
      for (int c2 = 0; c2 < 2; ++c2)
        av[rt][c2] = __builtin_amdgcn_mfma_f32_16x16x32_f16(pf, vf[ks][c2], av[rt][c2], 0, 0, 0);
    }
  }

  // store
  #pragma unroll
  for (int rt = 0; rt < 4; ++rt)
    #pragma unroll
    for (int c2 = 0; c2 < 2; ++c2)
      #pragma unroll
      for (int reg = 0; reg < 4; ++reg) {
        const int t = t0 + rt*16 + g*4 + reg;
        preh[((size_t)b*N_ + t)*C_ + hh*HD_ + c2*16 + l15] = (h16)av[rt][c2][reg];
      }
}

// ---------------------------------------------------------------------------
// Depthwise 3x3 conv on v; RMW preh in place
// ---------------------------------------------------------------------------
__global__ __launch_bounds__(256)
void dwc_kernel(const h16* __restrict__ v, const float* __restrict__ w9,
                const float* __restrict__ db, h16* __restrict__ preh)
{
  const int blk = blockIdx.x;
  const int y = blk % H_;
  const int rem = blk / H_;
  const int hh = rem & 7, b = rem >> 3;
  const int tid = threadIdx.x;
  __shared__ float Vr[3*W_*HD_];
  const size_t vbase = (size_t)rem * N_ * HD_;
  for (int i = tid; i < 3*W_*HD_; i += 256) {
    const int r = i / (W_*HD_);
    const int rest = i - r*(W_*HD_);
    const int yy = y + r - 1;
    Vr[i] = (yy >= 0 && yy < H_) ? (float)v[vbase + (size_t)yy*W_*HD_ + rest] : 0.f;
  }
  __syncthreads();
  const int d = tid & 31, xg = tid >> 5;
  const int c = hh*HD_ + d;
  float wr[9];
  #pragma unroll
  for (int j = 0; j < 9; ++j) wr[j] = w9[c*9 + j];
  const float bias = db[c];
  for (int x = xg; x < W_; x += 8) {
    float s = bias;
    #pragma unroll
    for (int ky = 0; ky < 3; ++ky) {
      #pragma unroll
      for (int kx = 0; kx < 3; ++kx) {
        const int xx = x + kx - 1;
        if (xx >= 0 && xx < W_) s += Vr[(ky*W_ + xx)*HD_ + d] * wr[ky*3 + kx];
      }
    }
    const size_t idx = ((size_t)b*N_ + y*W_ + x)*C_ + c;
    preh[idx] = (h16)((float)preh[idx] + s);
  }
}

// ---------------------------------------------------------------------------
extern "C" void kernel_launch(void* const* d_in, const int* in_sizes, int n_in,
                              void* d_out, int out_size, void* d_ws, size_t ws_size,
                              hipStream_t stream)
{
  (void)in_sizes; (void)n_in; (void)out_size;
  const float* x     = (const float*)d_in[0];
  const float* qkvw  = (const float*)d_in[1];
  const float* qkvb  = (const float*)d_in[2];
  const float* projw = (const float*)d_in[3];
  const float* projb = (const float*)d_in[4];
  const float* dwcw  = (const float*)d_in[5];
  const float* dwcb  = (const float*)d_in[6];
  const float* an    = (const float*)d_in[7];
  const float* na    = (const float*)d_in[8];
  const float* ah    = (const float*)d_in[9];
  const float* aw    = (const float*)d_in[10];
  const float* ha    = (const float*)d_in[11];
  const float* wa    = (const float*)d_in[12];

  const size_t EL = (size_t)B_*N_*C_;
  char* ws = (char*)d_ws;
  h16*   qh    = (h16*)(ws);
  h16*   kh    = (h16*)(ws + EL*2);
  h16*   vh    = (h16*)(ws + EL*4);
  h16*   xh    = (h16*)(ws + EL*6);
  float* posb  = (float*)(ws + EL*8);
  float* agbt  = (float*)(ws + EL*8 + (size_t)NH_*A_*N_*4);
  float* agent = (float*)(ws + EL*8 + (size_t)NH_*A_*N_*8);
  float* agv   = (float*)(ws + EL*8 + (size_t)NH_*A_*N_*8 + (size_t)B_*NH_*A_*HD_*4);
  h16*   wtq   = (h16*)(ws + EL*8 + (size_t)NH_*A_*N_*8 + (size_t)B_*NH_*A_*HD_*8);
  h16*   wtp   = (h16*)((char*)wtq + (size_t)768*256*2);
  const size_t NEED = EL*8 + (size_t)NH_*A_*N_*8 + (size_t)B_*NH_*A_*HD_*8
                    + (size_t)768*256*2 + (size_t)256*256*2;
  if (ws_size < NEED) return;

  float* pm   = (float*)xh;
  float* pl   = pm + (size_t)B_*NH_*NCH_*A_;
  float* pacc = pl + (size_t)B_*NH_*NCH_*A_;
  h16*   preh = kh;

  bias_kernel<<<dim3(NH_*A_), dim3(256), 0, stream>>>(an, na, ah, aw, ha, wa, posb, agbt);
  convx_kernel<<<dim3(4096), dim3(256), 0, stream>>>(x, xh);
  convw_kernel<<<dim3(1024), dim3(256), 0, stream>>>(qkvw, projw, wtq, wtp);
  gemm_qkv_mfma<<<dim3(6, 784), dim3(256), 0, stream>>>(xh, wtq, qkvb, qh, kh, vh);
  pool_kernel<<<dim3(B_*NH_*A_), dim3(64), 0, stream>>>(qh, agent);
  stage1a_mfma<<<dim3(B_*NH_*NCH_), dim3(256), 0, stream>>>(kh, vh, agent, posb, pm, pl, pacc);
  stage1b_kernel<<<dim3(B_*NH_), dim3(256), 0, stream>>>(pm, pl, pacc, agv);
  stage2_mfma<<<dim3(13, B_*NH_), dim3(256), 0, stream>>>(qh, agent, agv, agbt, preh);
  dwc_kernel<<<dim3(B_*NH_*H_), dim3(256), 0, stream>>>(vh, dwcw, dwcb, preh);
  gemm_proj_mfma<<<dim3(2, 784), dim3(256), 0, stream>>>(preh, wtp, projb, (float*)d_out);
}

// Round 6
// 332.267 us; speedup vs baseline: 5.3977x; 1.2017x over previous
//
#include <hip/hip_runtime.h>
#include <stdint.h>

#define B_ 32
#define H_ 56
#define W_ 56
#define N_ 3136
#define C_ 256
#define NH_ 8
#define HD_ 32
#define A_ 49
#define NCH_ 7
#define CHK_ 448
#define SCALE_ 0.17677669529663687f

typedef _Float16 h16;
typedef __attribute__((ext_vector_type(4))) _Float16 h16x4;
typedef __attribute__((ext_vector_type(8))) _Float16 h16x8;
typedef __attribute__((ext_vector_type(4))) float f32x4;

// global -> LDS direct DMA, 16B per lane
__device__ __forceinline__ void gload16(const void* g, void* l) {
  __builtin_amdgcn_global_load_lds(
      (const __attribute__((address_space(1))) unsigned int*)(uintptr_t)g,
      (__attribute__((address_space(3))) unsigned int*)(unsigned int)(uintptr_t)l,
      16, 0, 0);
}

// ---------------------------------------------------------------------------
// Bias precompute: position_bias [NH][A][N], agent_bias TRANSPOSED [NH][A][N]
// ---------------------------------------------------------------------------
__global__ __launch_bounds__(256)
void bias_kernel(const float* __restrict__ an, const float* __restrict__ na,
                 const float* __restrict__ ah, const float* __restrict__ aw,
                 const float* __restrict__ ha, const float* __restrict__ wa,
                 float* __restrict__ posb, float* __restrict__ agbt)
{
  const int hh = blockIdx.x / A_;
  const int ag = blockIdx.x % A_;
  __shared__ float an7[A_], na7[A_], ahv[H_], awv[W_], hav[H_], wav[W_];
  const int tid = threadIdx.x;
  if (tid < A_) {
    an7[tid] = an[(hh*A_ + ag)*A_ + tid];
    na7[tid] = na[(hh*A_ + ag)*A_ + tid];
  }
  if (tid < H_) {
    ahv[tid] = ah[(hh*A_ + ag)*H_ + tid];
    awv[tid] = aw[(hh*A_ + ag)*W_ + tid];
    hav[tid] = ha[(hh*H_ + tid)*A_ + ag];
    wav[tid] = wa[(hh*W_ + tid)*A_ + ag];
  }
  __syncthreads();
  for (int t = tid; t < N_; t += 256) {
    const int ty = t / W_, tx = t % W_;
    const float py = (ty + 0.5f)*0.125f - 0.5f;
    const float px = (tx + 0.5f)*0.125f - 0.5f;
    const int iy = (int)floorf(py), ix = (int)floorf(px);
    const float fy = py - (float)iy, fx = px - (float)ix;
    const int iy0 = min(max(iy, 0), 6), iy1 = min(iy + 1, 6);
    const int ix0 = min(max(ix, 0), 6), ix1 = min(ix + 1, 6);
    const float w00 = (1.f-fy)*(1.f-fx), w01 = (1.f-fy)*fx;
    const float w10 = fy*(1.f-fx),       w11 = fy*fx;
    const float ban = w00*an7[iy0*7+ix0] + w01*an7[iy0*7+ix1]
                    + w10*an7[iy1*7+ix0] + w11*an7[iy1*7+ix1];
    const float bna = w00*na7[iy0*7+ix0] + w01*na7[iy0*7+ix1]
                    + w10*na7[iy1*7+ix0] + w11*na7[iy1*7+ix1];
    posb[((size_t)(hh*A_ + ag))*N_ + t] = ban + ahv[ty] + awv[tx];
    agbt[((size_t)(hh*A_ + ag))*N_ + t] = bna + hav[ty] + wav[tx];
  }
}

// ---------------------------------------------------------------------------
// f32 -> f16 conversion of x
// ---------------------------------------------------------------------------
__global__ __launch_bounds__(256)
void convx_kernel(const float* __restrict__ x, h16* __restrict__ xh)
{
  const size_t nchunk = (size_t)B_*N_*C_/8;
  const size_t stride = (size_t)gridDim.x * 256;
  for (size_t i = blockIdx.x*256 + threadIdx.x; i < nchunk; i += stride) {
    const float4 u = ((const float4*)x)[i*2];
    const float4 v = ((const float4*)x)[i*2+1];
    h16x8 o;
    o[0]=(h16)u.x; o[1]=(h16)u.y; o[2]=(h16)u.z; o[3]=(h16)u.w;
    o[4]=(h16)v.x; o[5]=(h16)v.y; o[6]=(h16)v.z; o[7]=(h16)v.w;
    ((h16x8*)xh)[i] = o;
  }
}

// transpose+convert weights: wtq[768][256], wtp[256][256] f16,
// plus dwc weight table w9t[10][256] f16 (rows 0..8 = taps, row 9 = bias)
__global__ __launch_bounds__(256)
void convw_kernel(const float* __restrict__ qkvw, const float* __restrict__ projw,
                  const float* __restrict__ dwcw, const float* __restrict__ dwcb,
                  h16* __restrict__ wtq, h16* __restrict__ wtp, h16* __restrict__ w9t)
{
  const int bid = blockIdx.x, k = threadIdx.x;
  if (bid < 768) {
    wtq[bid*256 + k] = (h16)qkvw[(size_t)k*768 + bid];
  } else if (bid < 1024) {
    const int n = bid - 768;
    wtp[n*256 + k] = (h16)projw[(size_t)k*256 + n];
  } else {
    const int row = bid - 1024;            // 0..9
    w9t[row*256 + k] = (h16)(row < 9 ? dwcw[k*9 + row] : dwcb[k]);
  }
}

// ---------------------------------------------------------------------------
// f16 MFMA GEMM core: 128x128 tile, BK=32, 4 waves (2x2)
// ---------------------------------------------------------------------------
__device__ __forceinline__ void gemm_tile_128(
    const h16* __restrict__ Ag, const h16* __restrict__ Bg,
    int m0, int n0, char* lds, f32x4 acc[4][4], int lane, int wr, int wc, int tid)
{
  int aoff[4], boff[4];
  #pragma unroll
  for (int r = 0; r < 4; ++r) {
    const int row = wr*64 + r*16 + (lane & 15);
    const int ps  = (lane >> 4) ^ ((row >> 1) & 3);
    aoff[r] = row*64 + ps*16;
  }
  #pragma unroll
  for (int c = 0; c < 4; ++c) {
    const int nrow = wc*64 + c*16 + (lane & 15);
    const int ps   = (lane >> 4) ^ ((nrow >> 1) & 3);
    boff[c] = 8192 + nrow*64 + ps*16;
  }
  const int i0 = tid, i1 = tid + 256;
  const int r0 = i0 >> 2, s0 = (i0 & 3) ^ ((r0 >> 1) & 3);
  const int r1 = i1 >> 2, s1 = (i1 & 3) ^ ((r1 >> 1) & 3);

  for (int k0 = 0; k0 < 256; k0 += 32) {
    __syncthreads();
    gload16(Ag + (size_t)(m0 + r0)*256 + k0 + s0*8, lds + i0*16);
    gload16(Ag + (size_t)(m0 + r1)*256 + k0 + s1*8, lds + i1*16);
    gload16(Bg + (size_t)(n0 + r0)*256 + k0 + s0*8, lds + 8192 + i0*16);
    gload16(Bg + (size_t)(n0 + r1)*256 + k0 + s1*8, lds + 8192 + i1*16);
    __syncthreads();
    h16x8 af[4], bf[4];
    #pragma unroll
    for (int r = 0; r < 4; ++r) af[r] = *(const h16x8*)(lds + aoff[r]);
    #pragma unroll
    for (int c = 0; c < 4; ++c) bf[c] = *(const h16x8*)(lds + boff[c]);
    #pragma unroll
    for (int r = 0; r < 4; ++r)
      #pragma unroll
      for (int c = 0; c < 4; ++c)
        acc[r][c] = __builtin_amdgcn_mfma_f32_16x16x32_f16(af[r], bf[c], acc[r][c], 0, 0, 0);
  }
}

__global__ __launch_bounds__(256)
void gemm_qkv_mfma(const h16* __restrict__ xh, const h16* __restrict__ wtq,
                   const float* __restrict__ qkvb,
                   h16* __restrict__ q, h16* __restrict__ k, h16* __restrict__ v)
{
  __shared__ __align__(16) char lds[16384];
  const int tid = threadIdx.x, lane = tid & 63, wid = tid >> 6;
  const int wr = wid & 1, wc = wid >> 1;
  const int m0 = blockIdx.y * 128, n0 = blockIdx.x * 128;
  f32x4 acc[4][4] = {};
  gemm_tile_128(xh, wtq, m0, n0, lds, acc, lane, wr, wc, tid);
  #pragma unroll
  for (int r = 0; r < 4; ++r) {
    #pragma unroll
    for (int reg = 0; reg < 4; ++reg) {
      const int m = m0 + wr*64 + r*16 + (lane >> 4)*4 + reg;
      const int bb = m / N_, t = m % N_;
      #pragma unroll
      for (int c = 0; c < 4; ++c) {
        const int n = n0 + wc*64 + c*16 + (lane & 15);
        const float val = acc[r][c][reg] + qkvb[n];
        const int part = n >> 8, cc = n & 255, hh = cc >> 5, d = cc & 31;
        h16* dst = (part == 0) ? q : ((part == 1) ? k : v);
        dst[(((size_t)(bb*NH_ + hh))*N_ + t)*HD_ + d] = (h16)val;
      }
    }
  }
}

__global__ __launch_bounds__(256)
void gemm_proj_mfma(const h16* __restrict__ preh, const h16* __restrict__ wtp,
                    const float* __restrict__ projb, float* __restrict__ out)
{
  __shared__ __align__(16) char lds[16384];
  const int tid = threadIdx.x, lane = tid & 63, wid = tid >> 6;
  const int wr = wid & 1, wc = wid >> 1;
  const int m0 = blockIdx.y * 128, n0 = blockIdx.x * 128;
  f32x4 acc[4][4] = {};
  gemm_tile_128(preh, wtp, m0, n0, lds, acc, lane, wr, wc, tid);
  #pragma unroll
  for (int r = 0; r < 4; ++r) {
    #pragma unroll
    for (int reg = 0; reg < 4; ++reg) {
      const int m = m0 + wr*64 + r*16 + (lane >> 4)*4 + reg;
      #pragma unroll
      for (int c = 0; c < 4; ++c) {
        const int n = n0 + wc*64 + c*16 + (lane & 15);
        out[(size_t)m*256 + n] = acc[r][c][reg] + projb[n];
      }
    }
  }
}

// ---------------------------------------------------------------------------
// Agent pooling: 8x8 mean of q image -> agent [b][nh][49][32] (f32)
// ---------------------------------------------------------------------------
__global__ __launch_bounds__(64)
void pool_kernel(const h16* __restrict__ q, float* __restrict__ agent)
{
  const int blk = blockIdx.x;
  const int ag = blk % A_;
  const int rem = blk / A_;
  const int tid = threadIdx.x;
  const int d = tid & 31, half = tid >> 5;
  const int ay = ag / 7, ax = ag % 7;
  const size_t base = (size_t)rem * N_ * HD_;
  float s = 0.f;
  #pragma unroll
  for (int it = 0; it < 32; ++it) {
    const int yy = half*4 + (it >> 3), xx = it & 7;
    const int t = (ay*8 + yy)*W_ + ax*8 + xx;
    s += (float)q[base + (size_t)t*HD_ + d];
  }
  s += __shfl_down(s, 32, 64);
  if (tid < 32) agent[(size_t)rem*A_*HD_ + ag*HD_ + d] = s * (1.f/64.f);
}

// ---------------------------------------------------------------------------
// Stage 1a (MFMA): flash over 7 key-tiles of 64; M=64 (49 agents + pad)
// ---------------------------------------------------------------------------
__global__ __launch_bounds__(256)
void stage1a_mfma(const h16* __restrict__ kmat, const h16* __restrict__ vmat,
                  const float* __restrict__ agent, const float* __restrict__ posb,
                  float* __restrict__ pm, float* __restrict__ pl, float* __restrict__ pacc)
{
  __shared__ __align__(16) h16 Kl[64*32];
  __shared__ __align__(16) h16 Vt[32*72];
  __shared__ __align__(16) h16 Sl[64*72];
  const int tid = threadIdx.x, lane = tid & 63, wid = tid >> 6;
  const int bx = blockIdx.x;
  const int ch = bx % NCH_;
  const int rem = bx / NCH_;
  const int hh = rem & 7;
  const size_t kvbase = (size_t)rem * N_ * HD_;
  const size_t agbase = (size_t)rem * A_ * HD_;
  const float* pb = posb + (size_t)hh*A_*N_;

  const int arow = wid*16 + (lane & 15);
  const int kc = (lane >> 4) * 8;
  h16x8 a_ag = {};
  if (arow < A_) {
    #pragma unroll
    for (int j = 0; j < 8; ++j)
      a_ag[j] = (h16)(agent[agbase + (size_t)arow*HD_ + kc + j] * SCALE_);
  }

  const int r_k = tid >> 2;
  const int s_k = (tid & 3) ^ ((r_k >> 1) & 3);
  const int rowm = (lane >> 4) * 4;
  const int agrow0 = wid*16 + rowm;

  float m_r[4], l_r[4];
  #pragma unroll
  for (int r = 0; r < 4; ++r) { m_r[r] = -1e30f; l_r[r] = 0.f; }
  f32x4 accv[2] = {};

  for (int it = 0; it < 7; ++it) {
    const int t0 = ch*CHK_ + it*64;
    __syncthreads();
    gload16(kmat + kvbase + (size_t)(t0 + r_k)*HD_ + s_k*8, ((char*)Kl) + tid*16);
    const h16x8 vv = *(const h16x8*)&vmat[kvbase + (size_t)(t0 + lane)*HD_ + wid*8];
    #pragma unroll
    for (int j = 0; j < 8; ++j) Vt[(wid*8 + j)*72 + lane] = vv[j];
    __syncthreads();

    float sv[4][4];
    #pragma unroll
    for (int c = 0; c < 4; ++c) {
      const int kr = c*16 + (lane & 15);
      const int ph = (lane >> 4) ^ ((kr >> 1) & 3);
      const h16x8 bf = *(const h16x8*)&Kl[kr*32 + ph*8];
      const f32x4 sc = __builtin_amdgcn_mfma_f32_16x16x32_f16(a_ag, bf, (f32x4){0.f,0.f,0.f,0.f}, 0, 0, 0);
      #pragma unroll
      for (int reg = 0; reg < 4; ++reg) sv[reg][c] = sc[reg];
    }
    #pragma unroll
    for (int reg = 0; reg < 4; ++reg) {
      const int ag = agrow0 + reg;
      if (ag < A_) {
        #pragma unroll
        for (int c = 0; c < 4; ++c)
          sv[reg][c] += pb[(size_t)ag*N_ + t0 + c*16 + (lane & 15)];
      } else {
        #pragma unroll
        for (int c = 0; c < 4; ++c) sv[reg][c] = -1e30f;
      }
      float rm = fmaxf(fmaxf(sv[reg][0], sv[reg][1]), fmaxf(sv[reg][2], sv[reg][3]));
      rm = fmaxf(rm, __shfl_xor(rm, 1));
      rm = fmaxf(rm, __shfl_xor(rm, 2));
      rm = fmaxf(rm, __shfl_xor(rm, 4));
      rm = fmaxf(rm, __shfl_xor(rm, 8));
      const float mn = fmaxf(m_r[reg], rm);
      const float f = __expf(m_r[reg] - mn);
      m_r[reg] = mn;
      float rs = 0.f;
      #pragma unroll
      for (int c = 0; c < 4; ++c) {
        const float p = __expf(sv[reg][c] - mn);
        sv[reg][c] = p;
        rs += p;
      }
      rs += __shfl_xor(rs, 1); rs += __shfl_xor(rs, 2);
      rs += __shfl_xor(rs, 4); rs += __shfl_xor(rs, 8);
      l_r[reg] = l_r[reg]*f + rs;
      accv[0][reg] *= f;
      accv[1][reg] *= f;
      const int row = agrow0 + reg;
      #pragma unroll
      for (int c = 0; c < 4; ++c)
        Sl[row*72 + c*16 + (lane & 15)] = (h16)sv[reg][c];
    }
    __syncthreads();
    const int srow = wid*16 + (lane & 15);
    #pragma unroll
    for (int ks = 0; ks < 2; ++ks) {
      const h16x8 pf = *(const h16x8*)&Sl[srow*72 + ks*32 + (lane >> 4)*8];
      #pragma unroll
      for (int c2 = 0; c2 < 2; ++c2) {
        const int d = c2*16 + (lane & 15);
        const h16x8 vf = *(const h16x8*)&Vt[d*72 + ks*32 + (lane >> 4)*8];
        accv[c2] = __builtin_amdgcn_mfma_f32_16x16x32_f16(pf, vf, accv[c2], 0, 0, 0);
      }
    }
  }

  #pragma unroll
  for (int reg = 0; reg < 4; ++reg) {
    const int ag = agrow0 + reg;
    if (ag < A_) {
      if ((lane & 15) == 0) {
        pm[bx*A_ + ag] = m_r[reg];
        pl[bx*A_ + ag] = l_r[reg];
      }
      #pragma unroll
      for (int c2 = 0; c2 < 2; ++c2)
        pacc[(size_t)bx*(A_*HD_) + (size_t)ag*HD_ + c2*16 + (lane & 15)] = accv[c2][reg];
    }
  }
}

// Stage 1b: combine 7 chunk-partials -> agent_v
__global__ __launch_bounds__(256)
void stage1b_kernel(const float* __restrict__ pm, const float* __restrict__ pl,
                    const float* __restrict__ pacc, float* __restrict__ agv)
{
  const int rem = blockIdx.x;
  __shared__ float fs[NCH_*A_];
  const int tid = threadIdx.x;
  if (tid < A_) {
    float m = -1e30f;
    #pragma unroll
    for (int ch = 0; ch < NCH_; ++ch) m = fmaxf(m, pm[(rem*NCH_+ch)*A_ + tid]);
    float e[NCH_], l = 0.f;
    #pragma unroll
    for (int ch = 0; ch < NCH_; ++ch) {
      e[ch] = __expf(pm[(rem*NCH_+ch)*A_ + tid] - m);
      l += e[ch] * pl[(rem*NCH_+ch)*A_ + tid];
    }
    const float inv = 1.f / l;
    #pragma unroll
    for (int ch = 0; ch < NCH_; ++ch) fs[ch*A_ + tid] = e[ch] * inv;
  }
  __syncthreads();
  for (int idx = tid; idx < A_*HD_; idx += 256) {
    const int ag = idx >> 5;
    float s = 0.f;
    #pragma unroll
    for (int ch = 0; ch < NCH_; ++ch)
      s += fs[ch*A_ + ag] * pacc[((size_t)(rem*NCH_+ch))*(A_*HD_) + idx];
    agv[(size_t)rem*(A_*HD_) + idx] = s;
  }
}

// ---------------------------------------------------------------------------
// Stage 2 (MFMA): per wave 64 tokens x 64 agent-cols (49+pad).
// ---------------------------------------------------------------------------
__global__ __launch_bounds__(256)
void stage2_mfma(const h16* __restrict__ qmat, const float* __restrict__ agent,
                 const float* __restrict__ agv, const float* __restrict__ agbt,
                 h16* __restrict__ preh)
{
  __shared__ __align__(16) char lds2[45568];
  h16* Asw = (h16*)lds2;                       // [64][32] agent, swizzled, padded
  h16* AVt = (h16*)(lds2 + 4096);              // [32][72] agent_v transposed, padded
  const int tid = threadIdx.x, lane = tid & 63, wid = tid >> 6;
  const int b = blockIdx.y >> 3, hh = blockIdx.y & 7;
  const size_t agbase = (size_t)(b*NH_ + hh)*A_*HD_;

  for (int i = tid; i < 64*32; i += 256) Asw[i] = (h16)0.f;
  for (int i = tid; i < 32*72; i += 256) AVt[i] = (h16)0.f;
  __syncthreads();
  for (int i = tid; i < A_*HD_; i += 256) {
    const int a = i >> 5, d = i & 31;
    Asw[a*32 + (((d >> 3) ^ ((a >> 1) & 3)))*8 + (d & 7)] = (h16)(agent[agbase + i] * SCALE_);
    AVt[d*72 + a] = (h16)agv[agbase + i];
  }
  __syncthreads();

  const int t0 = blockIdx.x*256 + wid*64;
  if (t0 >= N_) return;

  h16* Pl = (h16*)(lds2 + 8704 + wid*9216);    // per-wave [64][72]
  const h16* qbase = qmat + (size_t)(b*NH_ + hh)*N_*HD_;
  const float* agbt_h = agbt + (size_t)hh*A_*N_;
  const int l15 = lane & 15, g = lane >> 4;

  h16x8 bq[4];
  #pragma unroll
  for (int c = 0; c < 4; ++c) {
    const int a = c*16 + l15;
    const int ph = g ^ ((a >> 1) & 3);
    bq[c] = *(const h16x8*)&Asw[a*32 + ph*8];
  }
  h16x8 aq[4];
  #pragma unroll
  for (int rt = 0; rt < 4; ++rt)
    aq[rt] = *(const h16x8*)&qbase[(size_t)(t0 + rt*16 + l15)*HD_ + g*8];

  f32x4 sc[4][4];
  #pragma unroll
  for (int rt = 0; rt < 4; ++rt)
    #pragma unroll
    for (int c = 0; c < 4; ++c)
      sc[rt][c] = __builtin_amdgcn_mfma_f32_16x16x32_f16(aq[rt], bq[c], (f32x4){0.f,0.f,0.f,0.f}, 0, 0, 0);

  #pragma unroll
  for (int rt = 0; rt < 4; ++rt) {
    float sv[4][4];
    #pragma unroll
    for (int c = 0; c < 4; ++c) {
      const int a = c*16 + l15;
      if (a < A_) {
        const float4 bias = *(const float4*)&agbt_h[(size_t)a*N_ + t0 + rt*16 + g*4];
        sv[0][c] = sc[rt][c][0] + bias.x;
        sv[1][c] = sc[rt][c][1] + bias.y;
        sv[2][c] = sc[rt][c][2] + bias.z;
        sv[3][c] = sc[rt][c][3] + bias.w;
      } else {
        sv[0][c] = sv[1][c] = sv[2][c] = sv[3][c] = -1e30f;
      }
    }
    #pragma unroll
    for (int reg = 0; reg < 4; ++reg) {
      float rm = fmaxf(fmaxf(sv[reg][0], sv[reg][1]), fmaxf(sv[reg][2], sv[reg][3]));
      rm = fmaxf(rm, __shfl_xor(rm, 1));
      rm = fmaxf(rm, __shfl_xor(rm, 2));
      rm = fmaxf(rm, __shfl_xor(rm, 4));
      rm = fmaxf(rm, __shfl_xor(rm, 8));
      float rs = 0.f;
      #pragma unroll
      for (int c = 0; c < 4; ++c) {
        const float p = __expf(sv[reg][c] - rm);
        sv[reg][c] = p;
        rs += p;
      }
      rs += __shfl_xor(rs, 1); rs += __shfl_xor(rs, 2);
      rs += __shfl_xor(rs, 4); rs += __shfl_xor(rs, 8);
      const float inv = 1.f / rs;
      const int row = rt*16 + g*4 + reg;
      #pragma unroll
      for (int c = 0; c < 4; ++c)
        Pl[row*72 + c*16 + l15] = (h16)(sv[reg][c] * inv);
    }
  }

  h16x8 vf[2][2];
  #pragma unroll
  for (int ks = 0; ks < 2; ++ks)
    #pragma unroll
    for (int c2 = 0; c2 < 2; ++c2)
      vf[ks][c2] = *(const h16x8*)&AVt[(c2*16 + l15)*72 + ks*32 + g*8];

  f32x4 av[4][2] = {};
  #pragma unroll
  for (int rt = 0; rt < 4; ++rt) {
    #pragma unroll
    for (int ks = 0; ks < 2; ++ks) {
      const h16x8 pf = *(const h16x8*)&Pl[(rt*16 + l15)*72 + ks*32 + g*8];
      #pragma unroll
      for (int c2 = 0; c2 < 2; ++c2)
        av[rt][c2] = __builtin_amdgcn_mfma_f32_16x16x32_f16(pf, vf[ks][c2], av[rt][c2], 0, 0, 0);
    }
  }

  #pragma unroll
  for (int rt = 0; rt < 4; ++rt)
    #pragma unroll
    for (int c2 = 0; c2 < 2; ++c2)
      #pragma unroll
      for (int reg = 0; reg < 4; ++reg) {
        const int t = t0 + rt*16 + g*4 + reg;
        preh[((size_t)b*N_ + t)*C_ + hh*HD_ + c2*16 + l15] = (h16)av[rt][c2][reg];
      }
}

// ---------------------------------------------------------------------------
// Depthwise 3x3 conv, LDS-free packed-f16: one thread per (b,h,t, 8-ch octet).
// 9 masked h16x8 taps straight from global (L2-served halo), RMW preh.
// ---------------------------------------------------------------------------
__global__ __launch_bounds__(256)
void dwc_kernel(const h16* __restrict__ v, const h16* __restrict__ w9t,
                h16* __restrict__ preh)
{
  const int lin = blockIdx.x*256 + threadIdx.x;   // [0, N_*4) per rem
  const int rem = blockIdx.y;                     // b*8+hh
  const int t = lin >> 2, c8 = lin & 3;
  const int y = t / W_, x = t - y*W_;
  const int hh = rem & 7, b = rem >> 3;
  const int cbase = hh*HD_ + c8*8;

  // weights + bias for these 8 channels (hot 5KB table)
  h16x8 wk[9];
  #pragma unroll
  for (int k = 0; k < 9; ++k)
    wk[k] = *(const h16x8*)&w9t[k*C_ + cbase];
  h16x8 acc = *(const h16x8*)&w9t[9*C_ + cbase];  // bias row

  const h16* vb = v + (size_t)rem*N_*HD_ + c8*8;
  #pragma unroll
  for (int ky = 0; ky < 3; ++ky) {
    #pragma unroll
    for (int kx = 0; kx < 3; ++kx) {
      const int yy = y + ky - 1, xx = x + kx - 1;
      const bool ok = ((unsigned)yy < (unsigned)H_) && ((unsigned)xx < (unsigned)W_);
      const int tt = ok ? (yy*W_ + xx) : t;
      const h16x8 vv = *(const h16x8*)&vb[(size_t)tt*HD_];
      const h16x8 w = ok ? wk[ky*3+kx] : (h16x8)(h16)0.f;
      acc += vv * w;
    }
  }

  h16x8* ph = (h16x8*)&preh[((size_t)b*N_ + t)*C_ + cbase];
  *ph += acc;
}

// ---------------------------------------------------------------------------
extern "C" void kernel_launch(void* const* d_in, const int* in_sizes, int n_in,
                              void* d_out, int out_size, void* d_ws, size_t ws_size,
                              hipStream_t stream)
{
  (void)in_sizes; (void)n_in; (void)out_size;
  const float* x     = (const float*)d_in[0];
  const float* qkvw  = (const float*)d_in[1];
  const float* qkvb  = (const float*)d_in[2];
  const float* projw = (const float*)d_in[3];
  const float* projb = (const float*)d_in[4];
  const float* dwcw  = (const float*)d_in[5];
  const float* dwcb  = (const float*)d_in[6];
  const float* an    = (const float*)d_in[7];
  const float* na    = (const float*)d_in[8];
  const float* ah    = (const float*)d_in[9];
  const float* aw    = (const float*)d_in[10];
  const float* ha    = (const float*)d_in[11];
  const float* wa    = (const float*)d_in[12];

  const size_t EL = (size_t)B_*N_*C_;
  char* ws = (char*)d_ws;
  h16*   qh    = (h16*)(ws);
  h16*   kh    = (h16*)(ws + EL*2);
  h16*   vh    = (h16*)(ws + EL*4);
  h16*   xh    = (h16*)(ws + EL*6);
  float* posb  = (float*)(ws + EL*8);
  float* agbt  = (float*)(ws + EL*8 + (size_t)NH_*A_*N_*4);
  float* agent = (float*)(ws + EL*8 + (size_t)NH_*A_*N_*8);
  float* agv   = (float*)(ws + EL*8 + (size_t)NH_*A_*N_*8 + (size_t)B_*NH_*A_*HD_*4);
  h16*   wtq   = (h16*)(ws + EL*8 + (size_t)NH_*A_*N_*8 + (size_t)B_*NH_*A_*HD_*8);
  h16*   wtp   = (h16*)((char*)wtq + (size_t)768*256*2);
  h16*   w9t   = (h16*)((char*)wtp + (size_t)256*256*2);
  const size_t NEED = EL*8 + (size_t)NH_*A_*N_*8 + (size_t)B_*NH_*A_*HD_*8
                    + (size_t)768*256*2 + (size_t)256*256*2 + (size_t)10*256*2;
  if (ws_size < NEED) return;

  float* pm   = (float*)xh;
  float* pl   = pm + (size_t)B_*NH_*NCH_*A_;
  float* pacc = pl + (size_t)B_*NH_*NCH_*A_;
  h16*   preh = kh;

  bias_kernel<<<dim3(NH_*A_), dim3(256), 0, stream>>>(an, na, ah, aw, ha, wa, posb, agbt);
  convx_kernel<<<dim3(4096), dim3(256), 0, stream>>>(x, xh);
  convw_kernel<<<dim3(1034), dim3(256), 0, stream>>>(qkvw, projw, dwcw, dwcb, wtq, wtp, w9t);
  gemm_qkv_mfma<<<dim3(6, 784), dim3(256), 0, stream>>>(xh, wtq, qkvb, qh, kh, vh);
  pool_kernel<<<dim3(B_*NH_*A_), dim3(64), 0, stream>>>(qh, agent);
  stage1a_mfma<<<dim3(B_*NH_*NCH_), dim3(256), 0, stream>>>(kh, vh, agent, posb, pm, pl, pacc);
  stage1b_kernel<<<dim3(B_*NH_), dim3(256), 0, stream>>>(pm, pl, pacc, agv);
  stage2_mfma<<<dim3(13, B_*NH_), dim3(256), 0, stream>>>(qh, agent, agv, agbt, preh);
  dwc_kernel<<<dim3(N_*4/256, B_*NH_), dim3(256), 0, stream>>>(vh, w9t, preh);
  gemm_proj_mfma<<<dim3(2, 784), dim3(256), 0, stream>>>(preh, wtp, projb, (float*)d_out);
}

// Round 7
// 321.497 us; speedup vs baseline: 5.5785x; 1.0335x over previous
//
#include <hip/hip_runtime.h>
#include <stdint.h>

#define B_ 32
#define H_ 56
#define W_ 56
#define N_ 3136
#define C_ 256
#define NH_ 8
#define HD_ 32
#define A_ 49
#define NCH_ 7
#define CHK_ 448
#define SCALE_ 0.17677669529663687f

typedef _Float16 h16;
typedef __attribute__((ext_vector_type(4))) _Float16 h16x4;
typedef __attribute__((ext_vector_type(8))) _Float16 h16x8;
typedef __attribute__((ext_vector_type(4))) float f32x4;

// global -> LDS direct DMA, 16B per lane
__device__ __forceinline__ void gload16(const void* g, void* l) {
  __builtin_amdgcn_global_load_lds(
      (const __attribute__((address_space(1))) unsigned int*)(uintptr_t)g,
      (__attribute__((address_space(3))) unsigned int*)(unsigned int)(uintptr_t)l,
      16, 0, 0);
}

// ---------------------------------------------------------------------------
// Bias precompute: position_bias [NH][A][N], agent_bias TRANSPOSED [NH][A][N]
// ---------------------------------------------------------------------------
__global__ __launch_bounds__(256)
void bias_kernel(const float* __restrict__ an, const float* __restrict__ na,
                 const float* __restrict__ ah, const float* __restrict__ aw,
                 const float* __restrict__ ha, const float* __restrict__ wa,
                 float* __restrict__ posb, float* __restrict__ agbt)
{
  const int hh = blockIdx.x / A_;
  const int ag = blockIdx.x % A_;
  __shared__ float an7[A_], na7[A_], ahv[H_], awv[W_], hav[H_], wav[W_];
  const int tid = threadIdx.x;
  if (tid < A_) {
    an7[tid] = an[(hh*A_ + ag)*A_ + tid];
    na7[tid] = na[(hh*A_ + ag)*A_ + tid];
  }
  if (tid < H_) {
    ahv[tid] = ah[(hh*A_ + ag)*H_ + tid];
    awv[tid] = aw[(hh*A_ + ag)*W_ + tid];
    hav[tid] = ha[(hh*H_ + tid)*A_ + ag];
    wav[tid] = wa[(hh*W_ + tid)*A_ + ag];
  }
  __syncthreads();
  for (int t = tid; t < N_; t += 256) {
    const int ty = t / W_, tx = t % W_;
    const float py = (ty + 0.5f)*0.125f - 0.5f;
    const float px = (tx + 0.5f)*0.125f - 0.5f;
    const int iy = (int)floorf(py), ix = (int)floorf(px);
    const float fy = py - (float)iy, fx = px - (float)ix;
    const int iy0 = min(max(iy, 0), 6), iy1 = min(iy + 1, 6);
    const int ix0 = min(max(ix, 0), 6), ix1 = min(ix + 1, 6);
    const float w00 = (1.f-fy)*(1.f-fx), w01 = (1.f-fy)*fx;
    const float w10 = fy*(1.f-fx),       w11 = fy*fx;
    const float ban = w00*an7[iy0*7+ix0] + w01*an7[iy0*7+ix1]
                    + w10*an7[iy1*7+ix0] + w11*an7[iy1*7+ix1];
    const float bna = w00*na7[iy0*7+ix0] + w01*na7[iy0*7+ix1]
                    + w10*na7[iy1*7+ix0] + w11*na7[iy1*7+ix1];
    posb[((size_t)(hh*A_ + ag))*N_ + t] = ban + ahv[ty] + awv[tx];
    agbt[((size_t)(hh*A_ + ag))*N_ + t] = bna + hav[ty] + wav[tx];
  }
}

// ---------------------------------------------------------------------------
// f32 -> f16 conversion of x
// ---------------------------------------------------------------------------
__global__ __launch_bounds__(256)
void convx_kernel(const float* __restrict__ x, h16* __restrict__ xh)
{
  const size_t nchunk = (size_t)B_*N_*C_/8;
  const size_t stride = (size_t)gridDim.x * 256;
  for (size_t i = blockIdx.x*256 + threadIdx.x; i < nchunk; i += stride) {
    const float4 u = ((const float4*)x)[i*2];
    const float4 v = ((const float4*)x)[i*2+1];
    h16x8 o;
    o[0]=(h16)u.x; o[1]=(h16)u.y; o[2]=(h16)u.z; o[3]=(h16)u.w;
    o[4]=(h16)v.x; o[5]=(h16)v.y; o[6]=(h16)v.z; o[7]=(h16)v.w;
    ((h16x8*)xh)[i] = o;
  }
}

// transpose+convert weights: wtq[768][256], wtp[256][256] f16,
// plus dwc weight table w9t[10][256] f16 (rows 0..8 = taps, row 9 = bias)
__global__ __launch_bounds__(256)
void convw_kernel(const float* __restrict__ qkvw, const float* __restrict__ projw,
                  const float* __restrict__ dwcw, const float* __restrict__ dwcb,
                  h16* __restrict__ wtq, h16* __restrict__ wtp, h16* __restrict__ w9t)
{
  const int bid = blockIdx.x, k = threadIdx.x;
  if (bid < 768) {
    wtq[bid*256 + k] = (h16)qkvw[(size_t)k*768 + bid];
  } else if (bid < 1024) {
    const int n = bid - 768;
    wtp[n*256 + k] = (h16)projw[(size_t)k*256 + n];
  } else {
    const int row = bid - 1024;            // 0..9
    w9t[row*256 + k] = (h16)(row < 9 ? dwcw[k*9 + row] : dwcb[k]);
  }
}

// ---------------------------------------------------------------------------
// f16 MFMA GEMM core: 128x128 tile, BK=32, 4 waves, DOUBLE-BUFFERED (T3-min):
// stage(next) issued before compute(cur); ONE barrier per K-step; the
// barrier's implicit vmcnt(0) lands after MFMA has hidden the load latency.
// ---------------------------------------------------------------------------
__device__ __forceinline__ void gemm_tile_128(
    const h16* __restrict__ Ag, const h16* __restrict__ Bg,
    int m0, int n0, char* lds, f32x4 acc[4][4], int lane, int wr, int wc, int tid)
{
  int aoff[4], boff[4];
  #pragma unroll
  for (int r = 0; r < 4; ++r) {
    const int row = wr*64 + r*16 + (lane & 15);
    const int ps  = (lane >> 4) ^ ((row >> 1) & 3);
    aoff[r] = row*64 + ps*16;
  }
  #pragma unroll
  for (int c = 0; c < 4; ++c) {
    const int nrow = wc*64 + c*16 + (lane & 15);
    const int ps   = (lane >> 4) ^ ((nrow >> 1) & 3);
    boff[c] = 8192 + nrow*64 + ps*16;
  }
  const int i0 = tid, i1 = tid + 256;
  const int r0 = i0 >> 2, s0 = (i0 & 3) ^ ((r0 >> 1) & 3);
  const int r1 = i1 >> 2, s1 = (i1 & 3) ^ ((r1 >> 1) & 3);

  auto stage = [&](int buf, int k0) {
    char* l = lds + buf*16384;
    gload16(Ag + (size_t)(m0 + r0)*256 + k0 + s0*8, l + i0*16);
    gload16(Ag + (size_t)(m0 + r1)*256 + k0 + s1*8, l + i1*16);
    gload16(Bg + (size_t)(n0 + r0)*256 + k0 + s0*8, l + 8192 + i0*16);
    gload16(Bg + (size_t)(n0 + r1)*256 + k0 + s1*8, l + 8192 + i1*16);
  };

  stage(0, 0);
  __syncthreads();                 // implicit vmcnt(0): buf0 ready
  int cur = 0;
  #pragma unroll
  for (int k0 = 0; k0 < 256; k0 += 32) {
    if (k0 + 32 < 256) stage(cur ^ 1, k0 + 32);   // prefetch next tile
    char* l = lds + cur*16384;
    h16x8 af[4], bf[4];
    #pragma unroll
    for (int r = 0; r < 4; ++r) af[r] = *(const h16x8*)(l + aoff[r]);
    #pragma unroll
    for (int c = 0; c < 4; ++c) bf[c] = *(const h16x8*)(l + boff[c]);
    #pragma unroll
    for (int r = 0; r < 4; ++r)
      #pragma unroll
      for (int c = 0; c < 4; ++c)
        acc[r][c] = __builtin_amdgcn_mfma_f32_16x16x32_f16(af[r], bf[c], acc[r][c], 0, 0, 0);
    __syncthreads();               // drains prefetch; next buffer ready
    cur ^= 1;
  }
}

// QKV: grid 4704 = 784 m-tiles x 6 n-tiles; XCD-bijective swizzle keeps all
// 6 n-blocks of one m-tile on the same XCD (one L2 fetch of the A tile).
__global__ __launch_bounds__(256)
void gemm_qkv_mfma(const h16* __restrict__ xh, const h16* __restrict__ wtq,
                   const float* __restrict__ qkvb,
                   h16* __restrict__ q, h16* __restrict__ k, h16* __restrict__ v)
{
  __shared__ __align__(16) char lds[32768];
  const int tid = threadIdx.x, lane = tid & 63, wid = tid >> 6;
  const int wr = wid & 1, wc = wid >> 1;
  const int bid = blockIdx.x;
  const int xcd = bid & 7, j = bid >> 3;           // j in [0,588)
  const int mt = xcd + 8*(j/6), nt = j - 6*(j/6);  // 784 = 98*8 exact
  const int m0 = mt*128, n0 = nt*128;
  f32x4 acc[4][4] = {};
  gemm_tile_128(xh, wtq, m0, n0, lds, acc, lane, wr, wc, tid);
  #pragma unroll
  for (int r = 0; r < 4; ++r) {
    #pragma unroll
    for (int reg = 0; reg < 4; ++reg) {
      const int m = m0 + wr*64 + r*16 + (lane >> 4)*4 + reg;
      const int bb = m / N_, t = m % N_;
      #pragma unroll
      for (int c = 0; c < 4; ++c) {
        const int n = n0 + wc*64 + c*16 + (lane & 15);
        const float val = acc[r][c][reg] + qkvb[n];
        const int part = n >> 8, cc = n & 255, hh = cc >> 5, d = cc & 31;
        h16* dst = (part == 0) ? q : ((part == 1) ? k : v);
        dst[(((size_t)(bb*NH_ + hh))*N_ + t)*HD_ + d] = (h16)val;
      }
    }
  }
}

// Proj: grid 1568 = 784 m-tiles x 2 n-tiles, same swizzle idea
__global__ __launch_bounds__(256)
void gemm_proj_mfma(const h16* __restrict__ preh, const h16* __restrict__ wtp,
                    const float* __restrict__ projb, float* __restrict__ out)
{
  __shared__ __align__(16) char lds[32768];
  const int tid = threadIdx.x, lane = tid & 63, wid = tid >> 6;
  const int wr = wid & 1, wc = wid >> 1;
  const int bid = blockIdx.x;
  const int xcd = bid & 7, j = bid >> 3;           // j in [0,196)
  const int mt = xcd + 8*(j >> 1), nt = j & 1;     // 784 = 98*8 exact
  const int m0 = mt*128, n0 = nt*128;
  f32x4 acc[4][4] = {};
  gemm_tile_128(preh, wtp, m0, n0, lds, acc, lane, wr, wc, tid);
  #pragma unroll
  for (int r = 0; r < 4; ++r) {
    #pragma unroll
    for (int reg = 0; reg < 4; ++reg) {
      const int m = m0 + wr*64 + r*16 + (lane >> 4)*4 + reg;
      #pragma unroll
      for (int c = 0; c < 4; ++c) {
        const int n = n0 + wc*64 + c*16 + (lane & 15);
        out[(size_t)m*256 + n] = acc[r][c][reg] + projb[n];
      }
    }
  }
}

// ---------------------------------------------------------------------------
// Agent pooling: 8x8 mean of q image -> agent [b][nh][49][32] (f32)
// ---------------------------------------------------------------------------
__global__ __launch_bounds__(64)
void pool_kernel(const h16* __restrict__ q, float* __restrict__ agent)
{
  const int blk = blockIdx.x;
  const int ag = blk % A_;
  const int rem = blk / A_;
  const int tid = threadIdx.x;
  const int d = tid & 31, half = tid >> 5;
  const int ay = ag / 7, ax = ag % 7;
  const size_t base = (size_t)rem * N_ * HD_;
  float s = 0.f;
  #pragma unroll
  for (int it = 0; it < 32; ++it) {
    const int yy = half*4 + (it >> 3), xx = it & 7;
    const int t = (ay*8 + yy)*W_ + ax*8 + xx;
    s += (float)q[base + (size_t)t*HD_ + d];
  }
  s += __shfl_down(s, 32, 64);
  if (tid < 32) agent[(size_t)rem*A_*HD_ + ag*HD_ + d] = s * (1.f/64.f);
}

// ---------------------------------------------------------------------------
// Stage 1a (MFMA): flash over 7 key-tiles of 64; M=64 (49 agents + pad)
// ---------------------------------------------------------------------------
__global__ __launch_bounds__(256)
void stage1a_mfma(const h16* __restrict__ kmat, const h16* __restrict__ vmat,
                  const float* __restrict__ agent, const float* __restrict__ posb,
                  float* __restrict__ pm, float* __restrict__ pl, float* __restrict__ pacc)
{
  __shared__ __align__(16) h16 Kl[64*32];
  __shared__ __align__(16) h16 Vt[32*72];
  __shared__ __align__(16) h16 Sl[64*72];
  const int tid = threadIdx.x, lane = tid & 63, wid = tid >> 6;
  const int bx = blockIdx.x;
  const int ch = bx % NCH_;
  const int rem = bx / NCH_;
  const int hh = rem & 7;
  const size_t kvbase = (size_t)rem * N_ * HD_;
  const size_t agbase = (size_t)rem * A_ * HD_;
  const float* pb = posb + (size_t)hh*A_*N_;

  const int arow = wid*16 + (lane & 15);
  const int kc = (lane >> 4) * 8;
  h16x8 a_ag = {};
  if (arow < A_) {
    #pragma unroll
    for (int j = 0; j < 8; ++j)
      a_ag[j] = (h16)(agent[agbase + (size_t)arow*HD_ + kc + j] * SCALE_);
  }

  const int r_k = tid >> 2;
  const int s_k = (tid & 3) ^ ((r_k >> 1) & 3);
  const int rowm = (lane >> 4) * 4;
  const int agrow0 = wid*16 + rowm;

  float m_r[4], l_r[4];
  #pragma unroll
  for (int r = 0; r < 4; ++r) { m_r[r] = -1e30f; l_r[r] = 0.f; }
  f32x4 accv[2] = {};

  for (int it = 0; it < 7; ++it) {
    const int t0 = ch*CHK_ + it*64;
    __syncthreads();
    gload16(kmat + kvbase + (size_t)(t0 + r_k)*HD_ + s_k*8, ((char*)Kl) + tid*16);
    const h16x8 vv = *(const h16x8*)&vmat[kvbase + (size_t)(t0 + lane)*HD_ + wid*8];
    #pragma unroll
    for (int j = 0; j < 8; ++j) Vt[(wid*8 + j)*72 + lane] = vv[j];
    __syncthreads();

    float sv[4][4];
    #pragma unroll
    for (int c = 0; c < 4; ++c) {
      const int kr = c*16 + (lane & 15);
      const int ph = (lane >> 4) ^ ((kr >> 1) & 3);
      const h16x8 bf = *(const h16x8*)&Kl[kr*32 + ph*8];
      const f32x4 sc = __builtin_amdgcn_mfma_f32_16x16x32_f16(a_ag, bf, (f32x4){0.f,0.f,0.f,0.f}, 0, 0, 0);
      #pragma unroll
      for (int reg = 0; reg < 4; ++reg) sv[reg][c] = sc[reg];
    }
    #pragma unroll
    for (int reg = 0; reg < 4; ++reg) {
      const int ag = agrow0 + reg;
      if (ag < A_) {
        #pragma unroll
        for (int c = 0; c < 4; ++c)
          sv[reg][c] += pb[(size_t)ag*N_ + t0 + c*16 + (lane & 15)];
      } else {
        #pragma unroll
        for (int c = 0; c < 4; ++c) sv[reg][c] = -1e30f;
      }
      float rm = fmaxf(fmaxf(sv[reg][0], sv[reg][1]), fmaxf(sv[reg][2], sv[reg][3]));
      rm = fmaxf(rm, __shfl_xor(rm, 1));
      rm = fmaxf(rm, __shfl_xor(rm, 2));
      rm = fmaxf(rm, __shfl_xor(rm, 4));
      rm = fmaxf(rm, __shfl_xor(rm, 8));
      const float mn = fmaxf(m_r[reg], rm);
      const float f = __expf(m_r[reg] - mn);
      m_r[reg] = mn;
      float rs = 0.f;
      #pragma unroll
      for (int c = 0; c < 4; ++c) {
        const float p = __expf(sv[reg][c] - mn);
        sv[reg][c] = p;
        rs += p;
      }
      rs += __shfl_xor(rs, 1); rs += __shfl_xor(rs, 2);
      rs += __shfl_xor(rs, 4); rs += __shfl_xor(rs, 8);
      l_r[reg] = l_r[reg]*f + rs;
      accv[0][reg] *= f;
      accv[1][reg] *= f;
      const int row = agrow0 + reg;
      #pragma unroll
      for (int c = 0; c < 4; ++c)
        Sl[row*72 + c*16 + (lane & 15)] = (h16)sv[reg][c];
    }
    __syncthreads();
    const int srow = wid*16 + (lane & 15);
    #pragma unroll
    for (int ks = 0; ks < 2; ++ks) {
      const h16x8 pf = *(const h16x8*)&Sl[srow*72 + ks*32 + (lane >> 4)*8];
      #pragma unroll
      for (int c2 = 0; c2 < 2; ++c2) {
        const int d = c2*16 + (lane & 15);
        const h16x8 vf = *(const h16x8*)&Vt[d*72 + ks*32 + (lane >> 4)*8];
        accv[c2] = __builtin_amdgcn_mfma_f32_16x16x32_f16(pf, vf, accv[c2], 0, 0, 0);
      }
    }
  }

  #pragma unroll
  for (int reg = 0; reg < 4; ++reg) {
    const int ag = agrow0 + reg;
    if (ag < A_) {
      if ((lane & 15) == 0) {
        pm[bx*A_ + ag] = m_r[reg];
        pl[bx*A_ + ag] = l_r[reg];
      }
      #pragma unroll
      for (int c2 = 0; c2 < 2; ++c2)
        pacc[(size_t)bx*(A_*HD_) + (size_t)ag*HD_ + c2*16 + (lane & 15)] = accv[c2][reg];
    }
  }
}

// Stage 1b: combine 7 chunk-partials -> agent_v
__global__ __launch_bounds__(256)
void stage1b_kernel(const float* __restrict__ pm, const float* __restrict__ pl,
                    const float* __restrict__ pacc, float* __restrict__ agv)
{
  const int rem = blockIdx.x;
  __shared__ float fs[NCH_*A_];
  const int tid = threadIdx.x;
  if (tid < A_) {
    float m = -1e30f;
    #pragma unroll
    for (int ch = 0; ch < NCH_; ++ch) m = fmaxf(m, pm[(rem*NCH_+ch)*A_ + tid]);
    float e[NCH_], l = 0.f;
    #pragma unroll
    for (int ch = 0; ch < NCH_; ++ch) {
      e[ch] = __expf(pm[(rem*NCH_+ch)*A_ + tid] - m);
      l += e[ch] * pl[(rem*NCH_+ch)*A_ + tid];
    }
    const float inv = 1.f / l;
    #pragma unroll
    for (int ch = 0; ch < NCH_; ++ch) fs[ch*A_ + tid] = e[ch] * inv;
  }
  __syncthreads();
  for (int idx = tid; idx < A_*HD_; idx += 256) {
    const int ag = idx >> 5;
    float s = 0.f;
    #pragma unroll
    for (int ch = 0; ch < NCH_; ++ch)
      s += fs[ch*A_ + ag] * pacc[((size_t)(rem*NCH_+ch))*(A_*HD_) + idx];
    agv[(size_t)rem*(A_*HD_) + idx] = s;
  }
}

// ---------------------------------------------------------------------------
// Stage 2 (MFMA): per wave 64 tokens x 64 agent-cols (49+pad).
// ---------------------------------------------------------------------------
__global__ __launch_bounds__(256)
void stage2_mfma(const h16* __restrict__ qmat, const float* __restrict__ agent,
                 const float* __restrict__ agv, const float* __restrict__ agbt,
                 h16* __restrict__ preh)
{
  __shared__ __align__(16) char lds2[45568];
  h16* Asw = (h16*)lds2;                       // [64][32] agent, swizzled, padded
  h16* AVt = (h16*)(lds2 + 4096);              // [32][72] agent_v transposed, padded
  const int tid = threadIdx.x, lane = tid & 63, wid = tid >> 6;
  const int b = blockIdx.y >> 3, hh = blockIdx.y & 7;
  const size_t agbase = (size_t)(b*NH_ + hh)*A_*HD_;

  for (int i = tid; i < 64*32; i += 256) Asw[i] = (h16)0.f;
  for (int i = tid; i < 32*72; i += 256) AVt[i] = (h16)0.f;
  __syncthreads();
  for (int i = tid; i < A_*HD_; i += 256) {
    const int a = i >> 5, d = i & 31;
    Asw[a*32 + (((d >> 3) ^ ((a >> 1) & 3)))*8 + (d & 7)] = (h16)(agent[agbase + i] * SCALE_);
    AVt[d*72 + a] = (h16)agv[agbase + i];
  }
  __syncthreads();

  const int t0 = blockIdx.x*256 + wid*64;
  if (t0 >= N_) return;

  h16* Pl = (h16*)(lds2 + 8704 + wid*9216);    // per-wave [64][72]
  const h16* qbase = qmat + (size_t)(b*NH_ + hh)*N_*HD_;
  const float* agbt_h = agbt + (size_t)hh*A_*N_;
  const int l15 = lane & 15, g = lane >> 4;

  h16x8 bq[4];
  #pragma unroll
  for (int c = 0; c < 4; ++c) {
    const int a = c*16 + l15;
    const int ph = g ^ ((a >> 1) & 3);
    bq[c] = *(const h16x8*)&Asw[a*32 + ph*8];
  }
  h16x8 aq[4];
  #pragma unroll
  for (int rt = 0; rt < 4; ++rt)
    aq[rt] = *(const h16x8*)&qbase[(size_t)(t0 + rt*16 + l15)*HD_ + g*8];

  f32x4 sc[4][4];
  #pragma unroll
  for (int rt = 0; rt < 4; ++rt)
    #pragma unroll
    for (int c = 0; c < 4; ++c)
      sc[rt][c] = __builtin_amdgcn_mfma_f32_16x16x32_f16(aq[rt], bq[c], (f32x4){0.f,0.f,0.f,0.f}, 0, 0, 0);

  #pragma unroll
  for (int rt = 0; rt < 4; ++rt) {
    float sv[4][4];
    #pragma unroll
    for (int c = 0; c < 4; ++c) {
      const int a = c*16 + l15;
      if (a < A_) {
        const float4 bias = *(const float4*)&agbt_h[(size_t)a*N_ + t0 + rt*16 + g*4];
        sv[0][c] = sc[rt][c][0] + bias.x;
        sv[1][c] = sc[rt][c][1] + bias.y;
        sv[2][c] = sc[rt][c][2] + bias.z;
        sv[3][c] = sc[rt][c][3] + bias.w;
      } else {
        sv[0][c] = sv[1][c] = sv[2][c] = sv[3][c] = -1e30f;
      }
    }
    #pragma unroll
    for (int reg = 0; reg < 4; ++reg) {
      float rm = fmaxf(fmaxf(sv[reg][0], sv[reg][1]), fmaxf(sv[reg][2], sv[reg][3]));
      rm = fmaxf(rm, __shfl_xor(rm, 1));
      rm = fmaxf(rm, __shfl_xor(rm, 2));
      rm = fmaxf(rm, __shfl_xor(rm, 4));
      rm = fmaxf(rm, __shfl_xor(rm, 8));
      float rs = 0.f;
      #pragma unroll
      for (int c = 0; c < 4; ++c) {
        const float p = __expf(sv[reg][c] - rm);
        sv[reg][c] = p;
        rs += p;
      }
      rs += __shfl_xor(rs, 1); rs += __shfl_xor(rs, 2);
      rs += __shfl_xor(rs, 4); rs += __shfl_xor(rs, 8);
      const float inv = 1.f / rs;
      const int row = rt*16 + g*4 + reg;
      #pragma unroll
      for (int c = 0; c < 4; ++c)
        Pl[row*72 + c*16 + l15] = (h16)(sv[reg][c] * inv);
    }
  }

  h16x8 vf[2][2];
  #pragma unroll
  for (int ks = 0; ks < 2; ++ks)
    #pragma unroll
    for (int c2 = 0; c2 < 2; ++c2)
      vf[ks][c2] = *(const h16x8*)&AVt[(c2*16 + l15)*72 + ks*32 + g*8];

  f32x4 av[4][2] = {};
  #pragma unroll
  for (int rt = 0; rt < 4; ++rt) {
    #pragma unroll
    for (int ks = 0; ks < 2; ++ks) {
      const h16x8 pf = *(const h16x8*)&Pl[(rt*16 + l15)*72 + ks*32 + g*8];
      #pragma unroll
      for (int c2 = 0; c2 < 2; ++c2)
        av[rt][c2] = __builtin_amdgcn_mfma_f32_16x16x32_f16(pf, vf[ks][c2], av[rt][c2], 0, 0, 0);
    }
  }

  #pragma unroll
  for (int rt = 0; rt < 4; ++rt)
    #pragma unroll
    for (int c2 = 0; c2 < 2; ++c2)
      #pragma unroll
      for (int reg = 0; reg < 4; ++reg) {
        const int t = t0 + rt*16 + g*4 + reg;
        preh[((size_t)b*N_ + t)*C_ + hh*HD_ + c2*16 + l15] = (h16)av[rt][c2][reg];
      }
}

// ---------------------------------------------------------------------------
// Depthwise 3x3 conv, LDS-free packed-f16: one thread per (b,h,t, 8-ch octet).
// ---------------------------------------------------------------------------
__global__ __launch_bounds__(256)
void dwc_kernel(const h16* __restrict__ v, const h16* __restrict__ w9t,
                h16* __restrict__ preh)
{
  const int lin = blockIdx.x*256 + threadIdx.x;   // [0, N_*4) per rem
  const int rem = blockIdx.y;                     // b*8+hh
  const int t = lin >> 2, c8 = lin & 3;
  const int y = t / W_, x = t - y*W_;
  const int hh = rem & 7, b = rem >> 3;
  const int cbase = hh*HD_ + c8*8;

  h16x8 wk[9];
  #pragma unroll
  for (int k = 0; k < 9; ++k)
    wk[k] = *(const h16x8*)&w9t[k*C_ + cbase];
  h16x8 acc = *(const h16x8*)&w9t[9*C_ + cbase];  // bias row

  const h16* vb = v + (size_t)rem*N_*HD_ + c8*8;
  #pragma unroll
  for (int ky = 0; ky < 3; ++ky) {
    #pragma unroll
    for (int kx = 0; kx < 3; ++kx) {
      const int yy = y + ky - 1, xx = x + kx - 1;
      const bool ok = ((unsigned)yy < (unsigned)H_) && ((unsigned)xx < (unsigned)W_);
      const int tt = ok ? (yy*W_ + xx) : t;
      const h16x8 vv = *(const h16x8*)&vb[(size_t)tt*HD_];
      const h16x8 w = ok ? wk[ky*3+kx] : (h16x8)(h16)0.f;
      acc += vv * w;
    }
  }

  h16x8* ph = (h16x8*)&preh[((size_t)b*N_ + t)*C_ + cbase];
  *ph += acc;
}

// ---------------------------------------------------------------------------
extern "C" void kernel_launch(void* const* d_in, const int* in_sizes, int n_in,
                              void* d_out, int out_size, void* d_ws, size_t ws_size,
                              hipStream_t stream)
{
  (void)in_sizes; (void)n_in; (void)out_size;
  const float* x     = (const float*)d_in[0];
  const float* qkvw  = (const float*)d_in[1];
  const float* qkvb  = (const float*)d_in[2];
  const float* projw = (const float*)d_in[3];
  const float* projb = (const float*)d_in[4];
  const float* dwcw  = (const float*)d_in[5];
  const float* dwcb  = (const float*)d_in[6];
  const float* an    = (const float*)d_in[7];
  const float* na    = (const float*)d_in[8];
  const float* ah    = (const float*)d_in[9];
  const float* aw    = (const float*)d_in[10];
  const float* ha    = (const float*)d_in[11];
  const float* wa    = (const float*)d_in[12];

  const size_t EL = (size_t)B_*N_*C_;
  char* ws = (char*)d_ws;
  h16*   qh    = (h16*)(ws);
  h16*   kh    = (h16*)(ws + EL*2);
  h16*   vh    = (h16*)(ws + EL*4);
  h16*   xh    = (h16*)(ws + EL*6);
  float* posb  = (float*)(ws + EL*8);
  float* agbt  = (float*)(ws + EL*8 + (size_t)NH_*A_*N_*4);
  float* agent = (float*)(ws + EL*8 + (size_t)NH_*A_*N_*8);
  float* agv   = (float*)(ws + EL*8 + (size_t)NH_*A_*N_*8 + (size_t)B_*NH_*A_*HD_*4);
  h16*   wtq   = (h16*)(ws + EL*8 + (size_t)NH_*A_*N_*8 + (size_t)B_*NH_*A_*HD_*8);
  h16*   wtp   = (h16*)((char*)wtq + (size_t)768*256*2);
  h16*   w9t   = (h16*)((char*)wtp + (size_t)256*256*2);
  const size_t NEED = EL*8 + (size_t)NH_*A_*N_*8 + (size_t)B_*NH_*A_*HD_*8
                    + (size_t)768*256*2 + (size_t)256*256*2 + (size_t)10*256*2;
  if (ws_size < NEED) return;

  float* pm   = (float*)xh;
  float* pl   = pm + (size_t)B_*NH_*NCH_*A_;
  float* pacc = pl + (size_t)B_*NH_*NCH_*A_;
  h16*   preh = kh;

  bias_kernel<<<dim3(NH_*A_), dim3(256), 0, stream>>>(an, na, ah, aw, ha, wa, posb, agbt);
  convx_kernel<<<dim3(4096), dim3(256), 0, stream>>>(x, xh);
  convw_kernel<<<dim3(1034), dim3(256), 0, stream>>>(qkvw, projw, dwcw, dwcb, wtq, wtp, w9t);
  gemm_qkv_mfma<<<dim3(4704), dim3(256), 0, stream>>>(xh, wtq, qkvb, qh, kh, vh);
  pool_kernel<<<dim3(B_*NH_*A_), dim3(64), 0, stream>>>(qh, agent);
  stage1a_mfma<<<dim3(B_*NH_*NCH_), dim3(256), 0, stream>>>(kh, vh, agent, posb, pm, pl, pacc);
  stage1b_kernel<<<dim3(B_*NH_), dim3(256), 0, stream>>>(pm, pl, pacc, agv);
  stage2_mfma<<<dim3(13, B_*NH_), dim3(256), 0, stream>>>(qh, agent, agv, agbt, preh);
  dwc_kernel<<<dim3(N_*4/256, B_*NH_), dim3(256), 0, stream>>>(vh, w9t, preh);
  gemm_proj_mfma<<<dim3(1568), dim3(256), 0, stream>>>(preh, wtp, projb, (float*)d_out);
}